// Round 10
// baseline (262.018 us; speedup 1.0000x reference)
//
#include <hip/hip_runtime.h>

typedef unsigned short u16;
typedef unsigned int u32;
typedef __attribute__((ext_vector_type(8))) short short8;
typedef __attribute__((ext_vector_type(4))) float f32x4;

#define NN 20000
#define EE 640000
#define SCAN_BLOCKS 80   // 80*256 = 20480 >= NN

__device__ inline u16 f2bf(float f) {
    u32 x = __float_as_uint(f);
    return (u16)((x + 0x7FFFu + ((x >> 16) & 1u)) >> 16);
}
__device__ inline float lo16(u32 w) { return __uint_as_float(w << 16); }
__device__ inline float hi16(u32 w) { return __uint_as_float(w & 0xFFFF0000u); }
__device__ inline u32 packbf(float a, float b) { return ((u32)f2bf(b) << 16) | (u32)f2bf(a); }

// ---------------- fused prep: zero cnt + cast x->bf16 + weight transpose/cast ----------------
#define ZP_N (NN * 8)
#define CX_N (NN * 32)
#define WP_N (128 * 1152 + 4 * 128 * 128 + 512)
__global__ __launch_bounds__(256) void prep_all(const float* __restrict__ x,
                                                const float* rw, const float* root,
                                                const float* Wq, const float* Wk,
                                                const float* Wv, const float* Ws,
                                                const float* bq, const float* bk,
                                                const float* bv, const float* bs,
                                                int* __restrict__ cnt, u16* __restrict__ xb,
                                                u16* wt1, u16* wt2, float* bcat) {
    int idx = blockIdx.x * 256 + threadIdx.x;
    if (idx < ZP_N) {
        cnt[idx] = 0;
        return;
    }
    idx -= ZP_N;
    if (idx < CX_N) {
        float4 v = *(const float4*)(x + (size_t)idx * 4);
        uint2 o;
        o.x = packbf(v.x, v.y);
        o.y = packbf(v.z, v.w);
        *(uint2*)(xb + (size_t)idx * 4) = o;
        return;
    }
    idx -= CX_N;
    const int S1 = 128 * 1152, S2 = 4 * 128 * 128;
    if (idx < S1) {
        int o = idx / 1152, k = idx - o * 1152;
        float v = (k < 1024) ? rw[k * 128 + o] : root[(k - 1024) * 128 + o];
        wt1[idx] = f2bf(v);
    } else if (idx < S1 + S2) {
        int j = idx - S1;
        int y = j >> 14, rem = j & 16383, o = rem >> 7, i = rem & 127;
        const float* W = (y == 0) ? Wq : (y == 1) ? Wk : (y == 2) ? Wv : Ws;
        wt2[j] = f2bf(W[i * 128 + o]);
    } else if (idx < S1 + S2 + 512) {
        int j = idx - (S1 + S2);
        int y = j >> 7, c = j & 127;
        const float* b = (y == 0) ? bq : (y == 1) ? bk : (y == 2) ? bv : bs;
        bcat[j] = b[c];
    }
}

// ---------------- CSR build: one atomic per edge, 8 edges/thread ----------------
__global__ void count_rank(const int* __restrict__ ei, const int* __restrict__ et,
                           int* __restrict__ cnt, int* __restrict__ rank) {
    int base = blockIdx.x * 2048 + threadIdx.x;
#pragma unroll
    for (int j = 0; j < 8; j++) {
        int e = base + j * 256;
        if (e < EE) {
            int dst = ei[EE + e];
            int r = et[e];
            rank[e] = atomicAdd(&cnt[dst * 8 + r], 1);
        }
    }
}

// ---------------- parallel 3-phase scan ----------------
__global__ __launch_bounds__(256) void scan_phase1(const int* __restrict__ cnt,
                                                   int* __restrict__ deg_pref,
                                                   int* __restrict__ blk_sums) {
    __shared__ int lds[256];
    int t = threadIdx.x;
    int n = blockIdx.x * 256 + t;
    int d = 0;
    if (n < NN) {
        int4 c0 = *(const int4*)(cnt + n * 8);
        int4 c1 = *(const int4*)(cnt + n * 8 + 4);
        d = c0.x + c0.y + c0.z + c0.w + c1.x + c1.y + c1.z + c1.w;
    }
    lds[t] = d;
    __syncthreads();
    for (int o = 1; o < 256; o <<= 1) {
        int v = (t >= o) ? lds[t - o] : 0;
        __syncthreads();
        lds[t] += v;
        __syncthreads();
    }
    if (n < NN) deg_pref[n] = lds[t];
    if (t == 255) blk_sums[blockIdx.x] = lds[255];
}

__global__ void scan_phase2(int* __restrict__ blk_sums) {
    __shared__ int lds[128];
    int t = threadIdx.x;
    int v = (t < SCAN_BLOCKS) ? blk_sums[t] : 0;
    lds[t] = v;
    __syncthreads();
    for (int o = 1; o < 128; o <<= 1) {
        int a = (t >= o) ? lds[t - o] : 0;
        __syncthreads();
        lds[t] += a;
        __syncthreads();
    }
    if (t < SCAN_BLOCKS) blk_sums[t] = lds[t] - v;   // exclusive
}

__global__ __launch_bounds__(256) void scan_phase3(const int* __restrict__ cnt,
                                                   const int* __restrict__ deg_pref,
                                                   const int* __restrict__ blk_sums,
                                                   int* __restrict__ row_off,
                                                   int* __restrict__ srt) {
    int n = blockIdx.x * 256 + threadIdx.x;
    if (n >= NN) return;
    int4 c0 = *(const int4*)(cnt + n * 8);
    int4 c1 = *(const int4*)(cnt + n * 8 + 4);
    int deg = c0.x + c0.y + c0.z + c0.w + c1.x + c1.y + c1.z + c1.w;
    int start = blk_sums[blockIdx.x] + deg_pref[n] - deg;
    row_off[n] = start;
    int sub = start;
    int o[8];
    o[0] = sub; sub += c0.x;
    o[1] = sub; sub += c0.y;
    o[2] = sub; sub += c0.z;
    o[3] = sub; sub += c0.w;
    o[4] = sub; sub += c1.x;
    o[5] = sub; sub += c1.y;
    o[6] = sub; sub += c1.z;
    o[7] = sub; sub += c1.w;
    *(int4*)(srt + n * 8) = make_int4(o[0], o[1], o[2], o[3]);
    *(int4*)(srt + n * 8 + 4) = make_int4(o[4], o[5], o[6], o[7]);
    if (n == NN - 1) row_off[NN] = sub;
}

// atomic-free scatter, 8 edges/thread
__global__ void scatter_kernel(const int* __restrict__ ei, const int* __restrict__ et,
                               const int* __restrict__ srt, const int* __restrict__ rank,
                               int* __restrict__ es) {
    int base = blockIdx.x * 2048 + threadIdx.x;
#pragma unroll
    for (int j = 0; j < 8; j++) {
        int e = base + j * 256;
        if (e < EE) {
            int dst = ei[EE + e];
            int src = ei[e];
            int r = et[e];
            es[srt[dst * 8 + r] + rank[e]] = src;
        }
    }
}

// ---------------- fused RGCN aggregate + GEMM1 (BM=32, K=1152=9x128, relu) ----------------
// A k-slice r<8: mean_{e in (node,r)} xb[src]; r==8: xb[node].  C = relu(A*Bt^T + bias)
__global__ __launch_bounds__(256) void rgcn_gemm(const u16* __restrict__ xb,
                                                 const int* __restrict__ srt,
                                                 const int* __restrict__ cnt,
                                                 const int* __restrict__ es,
                                                 const u16* __restrict__ Bt,
                                                 const float* __restrict__ bias,
                                                 u16* __restrict__ C, int rows) {
    __shared__ u16 As[32 * 136];
    __shared__ u16 Bs[128 * 136];
    int tid = threadIdx.x;
    int g = tid >> 4;        // 16-lane group id (0..15)
    int lane16 = tid & 15;   // 8 dims/lane
    int w = tid >> 6;
    int lane = tid & 63;
    int quad = lane >> 4;
    int ml = lane & 15;
    int mt = w & 1;          // m-tile (0..1)
    int nq = w >> 1;         // n-quarter (0..1)
    int block_m = blockIdx.x * 32;

    f32x4 acc[4];
#pragma unroll
    for (int i = 0; i < 4; i++) acc[i] = (f32x4){0.f, 0.f, 0.f, 0.f};

    int rbase = tid >> 4;
    int cb = (tid & 15) * 8;

#pragma unroll 1
    for (int kb = 0; kb < 9; kb++) {
        // stage B tile (128 x 128 slice of wt1)
#pragma unroll
        for (int rep = 0; rep < 8; rep++) {
            int r = rbase + rep * 16;
            short8 val = *(const short8*)(Bt + (long)r * 1152 + kb * 128 + cb);
            *(short8*)(Bs + r * 136 + cb) = val;
        }
        // stage A tile: each 16-lane group aggregates 2 nodes for this k-slice
#pragma unroll
        for (int rep = 0; rep < 2; rep++) {
            int nl = g + rep * 16;
            int node = block_m + nl;
            uint4 ow = {0u, 0u, 0u, 0u};
            if (node < rows) {
                if (kb == 8) {
                    ow = *(const uint4*)(xb + (long)node * 128 + lane16 * 8);
                } else {
                    int c = cnt[node * 8 + kb];
                    int p0 = srt[node * 8 + kb];
                    float inv = 1.0f / (float)(c > 1 ? c : 1);
                    float a0 = 0.f, a1 = 0.f, a2 = 0.f, a3 = 0.f,
                          a4 = 0.f, a5 = 0.f, a6 = 0.f, a7 = 0.f;
                    int i = 0;
                    for (; i + 4 <= c; i += 4) {
                        int s0 = es[p0 + i], s1 = es[p0 + i + 1],
                            s2 = es[p0 + i + 2], s3 = es[p0 + i + 3];
                        uint4 w0 = *(const uint4*)(xb + (long)s0 * 128 + lane16 * 8);
                        uint4 w1 = *(const uint4*)(xb + (long)s1 * 128 + lane16 * 8);
                        uint4 w2 = *(const uint4*)(xb + (long)s2 * 128 + lane16 * 8);
                        uint4 w3 = *(const uint4*)(xb + (long)s3 * 128 + lane16 * 8);
                        a0 += (lo16(w0.x) + lo16(w1.x)) + (lo16(w2.x) + lo16(w3.x));
                        a1 += (hi16(w0.x) + hi16(w1.x)) + (hi16(w2.x) + hi16(w3.x));
                        a2 += (lo16(w0.y) + lo16(w1.y)) + (lo16(w2.y) + lo16(w3.y));
                        a3 += (hi16(w0.y) + hi16(w1.y)) + (hi16(w2.y) + hi16(w3.y));
                        a4 += (lo16(w0.z) + lo16(w1.z)) + (lo16(w2.z) + lo16(w3.z));
                        a5 += (hi16(w0.z) + hi16(w1.z)) + (hi16(w2.z) + hi16(w3.z));
                        a6 += (lo16(w0.w) + lo16(w1.w)) + (lo16(w2.w) + lo16(w3.w));
                        a7 += (hi16(w0.w) + hi16(w1.w)) + (hi16(w2.w) + hi16(w3.w));
                    }
                    for (; i < c; i++) {
                        int s = es[p0 + i];
                        uint4 wv = *(const uint4*)(xb + (long)s * 128 + lane16 * 8);
                        a0 += lo16(wv.x); a1 += hi16(wv.x); a2 += lo16(wv.y); a3 += hi16(wv.y);
                        a4 += lo16(wv.z); a5 += hi16(wv.z); a6 += lo16(wv.w); a7 += hi16(wv.w);
                    }
                    ow.x = packbf(a0 * inv, a1 * inv);
                    ow.y = packbf(a2 * inv, a3 * inv);
                    ow.z = packbf(a4 * inv, a5 * inv);
                    ow.w = packbf(a6 * inv, a7 * inv);
                }
            }
            *(uint4*)(As + nl * 136 + lane16 * 8) = ow;
        }
        __syncthreads();
#pragma unroll
        for (int ks = 0; ks < 4; ks++) {
            short8 af = *(const short8*)(As + (mt * 16 + ml) * 136 + ks * 32 + quad * 8);
#pragma unroll
            for (int nt = 0; nt < 4; nt++) {
                short8 bfr = *(const short8*)(Bs + (nq * 64 + nt * 16 + ml) * 136 + ks * 32 + quad * 8);
                acc[nt] = __builtin_amdgcn_mfma_f32_16x16x32_bf16(af, bfr, acc[nt], 0, 0, 0);
            }
        }
        __syncthreads();
    }
#pragma unroll
    for (int nt = 0; nt < 4; nt++) {
        int col = nq * 64 + nt * 16 + ml;
        float bv = bias[col];
#pragma unroll
        for (int i = 0; i < 4; i++) {
            int gr = block_m + mt * 16 + quad * 4 + i;
            if (gr < rows) {
                float vv = fmaxf(acc[nt][i] + bv, 0.f);
                C[(long)gr * 128 + col] = f2bf(vv);
            }
        }
    }
}

// ---------------- GEMM2 (q / kv-interleaved / skip): BM=64, K=128 ----------------
__global__ __launch_bounds__(256) void gemm_qkvs(const u16* __restrict__ A,
                                                 const u16* __restrict__ Bt,
                                                 const float* __restrict__ bias,
                                                 u16* __restrict__ Cq, u16* __restrict__ Ckv,
                                                 u16* __restrict__ Cs, int rows) {
    int y = blockIdx.y;
    Bt += (long)y * 128 * 128;
    bias += y * 128;
    u16* C;
    int ldc;
    if (y == 0) { C = Cq; ldc = 128; }
    else if (y == 1) { C = Ckv; ldc = 256; }
    else if (y == 2) { C = Ckv + 128; ldc = 256; }
    else { C = Cs; ldc = 128; }

    __shared__ u16 As[64 * 136];
    __shared__ u16 Bs[128 * 136];
    int tid = threadIdx.x;
    int w = tid >> 6;
    int lane = tid & 63;
    int quad = lane >> 4;
    int ml = lane & 15;
    int block_m = blockIdx.x * 64;

    f32x4 acc[8];
#pragma unroll
    for (int i = 0; i < 8; i++) acc[i] = (f32x4){0.f, 0.f, 0.f, 0.f};

    int rbase = tid >> 4;
    int cb = (tid & 15) * 8;

#pragma unroll
    for (int rep = 0; rep < 4; rep++) {
        int r = rbase + rep * 16;
        int gr = block_m + r;
        short8 val = {};
        if (gr < rows) val = *(const short8*)(A + (long)gr * 128 + cb);
        *(short8*)(As + r * 136 + cb) = val;
    }
#pragma unroll
    for (int rep = 0; rep < 8; rep++) {
        int r = rbase + rep * 16;
        short8 val = *(const short8*)(Bt + (long)r * 128 + cb);
        *(short8*)(Bs + r * 136 + cb) = val;
    }
    __syncthreads();
#pragma unroll
    for (int ks = 0; ks < 4; ks++) {
        short8 af = *(const short8*)(As + (w * 16 + ml) * 136 + ks * 32 + quad * 8);
#pragma unroll
        for (int nt = 0; nt < 8; nt++) {
            short8 bfr = *(const short8*)(Bs + (nt * 16 + ml) * 136 + ks * 32 + quad * 8);
            acc[nt] = __builtin_amdgcn_mfma_f32_16x16x32_bf16(af, bfr, acc[nt], 0, 0, 0);
        }
    }
#pragma unroll
    for (int nt = 0; nt < 8; nt++) {
        int col = nt * 16 + ml;
        float bv = bias[col];
#pragma unroll
        for (int i = 0; i < 4; i++) {
            int gr = block_m + w * 16 + quad * 4 + i;
            if (gr < rows) {
                C[(long)gr * ldc + col] = f2bf(acc[nt][i] + bv);
            }
        }
    }
}

// ---------------- attention: 16-lane/node, direct-exp softmax, fused KV ----------------
__global__ __launch_bounds__(256) void attn_kernel(const u16* __restrict__ q,
                                                   const u16* __restrict__ kv,
                                                   const u16* __restrict__ skip,
                                                   const int* __restrict__ row_off,
                                                   const int* __restrict__ es,
                                                   float* __restrict__ out) {
    int node = blockIdx.x * 16 + (threadIdx.x >> 4);
    int lane = threadIdx.x & 15;     // 8 dims/lane
    if (node >= NN) return;
    int p0 = row_off[node], p1 = row_off[node + 1];
    uint4 qw = *(const uint4*)(q + (long)node * 128 + lane * 8);
    float q0 = lo16(qw.x), q1 = hi16(qw.x), q2 = lo16(qw.y), q3 = hi16(qw.y);
    float q4 = lo16(qw.z), q5 = hi16(qw.z), q6 = lo16(qw.w), q7 = hi16(qw.w);
    const float SC = 0.08838834764831845f;  // 1/sqrt(128)
    float l = 0.f;
    float a0 = 0.f, a1 = 0.f, a2 = 0.f, a3 = 0.f, a4 = 0.f, a5 = 0.f, a6 = 0.f, a7 = 0.f;
    int p = p0;
    for (; p + 4 <= p1; p += 4) {
        const u16* b0 = kv + (long)es[p] * 256 + lane * 8;
        const u16* b1 = kv + (long)es[p + 1] * 256 + lane * 8;
        const u16* b2 = kv + (long)es[p + 2] * 256 + lane * 8;
        const u16* b3 = kv + (long)es[p + 3] * 256 + lane * 8;
        uint4 k0 = *(const uint4*)b0;
        uint4 k1 = *(const uint4*)b1;
        uint4 k2 = *(const uint4*)b2;
        uint4 k3 = *(const uint4*)b3;
        uint4 v0 = *(const uint4*)(b0 + 128);
        uint4 v1 = *(const uint4*)(b1 + 128);
        uint4 v2 = *(const uint4*)(b2 + 128);
        uint4 v3 = *(const uint4*)(b3 + 128);
        float t0 = q0 * lo16(k0.x) + q1 * hi16(k0.x) + q2 * lo16(k0.y) + q3 * hi16(k0.y) +
                   q4 * lo16(k0.z) + q5 * hi16(k0.z) + q6 * lo16(k0.w) + q7 * hi16(k0.w);
        float t1 = q0 * lo16(k1.x) + q1 * hi16(k1.x) + q2 * lo16(k1.y) + q3 * hi16(k1.y) +
                   q4 * lo16(k1.z) + q5 * hi16(k1.z) + q6 * lo16(k1.w) + q7 * hi16(k1.w);
        float t2 = q0 * lo16(k2.x) + q1 * hi16(k2.x) + q2 * lo16(k2.y) + q3 * hi16(k2.y) +
                   q4 * lo16(k2.z) + q5 * hi16(k2.z) + q6 * lo16(k2.w) + q7 * hi16(k2.w);
        float t3 = q0 * lo16(k3.x) + q1 * hi16(k3.x) + q2 * lo16(k3.y) + q3 * hi16(k3.y) +
                   q4 * lo16(k3.z) + q5 * hi16(k3.z) + q6 * lo16(k3.w) + q7 * hi16(k3.w);
#pragma unroll
        for (int off = 8; off >= 1; off >>= 1) {
            t0 += __shfl_xor(t0, off, 16);
            t1 += __shfl_xor(t1, off, 16);
            t2 += __shfl_xor(t2, off, 16);
            t3 += __shfl_xor(t3, off, 16);
        }
        float w0 = __expf(fminf(t0 * SC, 70.f));
        float w1 = __expf(fminf(t1 * SC, 70.f));
        float w2 = __expf(fminf(t2 * SC, 70.f));
        float w3 = __expf(fminf(t3 * SC, 70.f));
        l += (w0 + w1) + (w2 + w3);
        a0 += w0 * lo16(v0.x) + w1 * lo16(v1.x) + w2 * lo16(v2.x) + w3 * lo16(v3.x);
        a1 += w0 * hi16(v0.x) + w1 * hi16(v1.x) + w2 * hi16(v2.x) + w3 * hi16(v3.x);
        a2 += w0 * lo16(v0.y) + w1 * lo16(v1.y) + w2 * lo16(v2.y) + w3 * lo16(v3.y);
        a3 += w0 * hi16(v0.y) + w1 * hi16(v1.y) + w2 * hi16(v2.y) + w3 * hi16(v3.y);
        a4 += w0 * lo16(v0.z) + w1 * lo16(v1.z) + w2 * lo16(v2.z) + w3 * lo16(v3.z);
        a5 += w0 * hi16(v0.z) + w1 * hi16(v1.z) + w2 * hi16(v2.z) + w3 * hi16(v3.z);
        a6 += w0 * lo16(v0.w) + w1 * lo16(v1.w) + w2 * lo16(v2.w) + w3 * lo16(v3.w);
        a7 += w0 * hi16(v0.w) + w1 * hi16(v1.w) + w2 * hi16(v2.w) + w3 * hi16(v3.w);
    }
    for (; p < p1; p++) {
        const u16* b = kv + (long)es[p] * 256 + lane * 8;
        uint4 kw = *(const uint4*)b;
        uint4 vw = *(const uint4*)(b + 128);
        float t = q0 * lo16(kw.x) + q1 * hi16(kw.x) + q2 * lo16(kw.y) + q3 * hi16(kw.y) +
                  q4 * lo16(kw.z) + q5 * hi16(kw.z) + q6 * lo16(kw.w) + q7 * hi16(kw.w);
#pragma unroll
        for (int off = 8; off >= 1; off >>= 1) t += __shfl_xor(t, off, 16);
        float w = __expf(fminf(t * SC, 70.f));
        l += w;
        a0 += w * lo16(vw.x);
        a1 += w * hi16(vw.x);
        a2 += w * lo16(vw.y);
        a3 += w * hi16(vw.y);
        a4 += w * lo16(vw.z);
        a5 += w * hi16(vw.z);
        a6 += w * lo16(vw.w);
        a7 += w * hi16(vw.w);
    }
    float invl = (l > 0.f) ? 1.0f / l : 0.f;
    uint4 sw = *(const uint4*)(skip + (long)node * 128 + lane * 8);
    float4 oa, ob;
    oa.x = fmaxf(a0 * invl + lo16(sw.x), 0.f);
    oa.y = fmaxf(a1 * invl + hi16(sw.x), 0.f);
    oa.z = fmaxf(a2 * invl + lo16(sw.y), 0.f);
    oa.w = fmaxf(a3 * invl + hi16(sw.y), 0.f);
    ob.x = fmaxf(a4 * invl + lo16(sw.z), 0.f);
    ob.y = fmaxf(a5 * invl + hi16(sw.z), 0.f);
    ob.z = fmaxf(a6 * invl + lo16(sw.w), 0.f);
    ob.w = fmaxf(a7 * invl + hi16(sw.w), 0.f);
    *(float4*)(out + (long)node * 128 + lane * 8) = oa;
    *(float4*)(out + (long)node * 128 + lane * 8 + 4) = ob;
}

extern "C" void kernel_launch(void* const* d_in, const int* in_sizes, int n_in,
                              void* d_out, int out_size, void* d_ws, size_t ws_size,
                              hipStream_t stream) {
    const float* x = (const float*)d_in[0];
    const int* ei = (const int*)d_in[1];
    const int* et = (const int*)d_in[2];
    const float* rw = (const float*)d_in[3];
    const float* root = (const float*)d_in[4];
    const float* rbias = (const float*)d_in[5];
    const float* Wq = (const float*)d_in[6];
    const float* bq = (const float*)d_in[7];
    const float* Wk = (const float*)d_in[8];
    const float* bk = (const float*)d_in[9];
    const float* Wv = (const float*)d_in[10];
    const float* bv = (const float*)d_in[11];
    const float* Ws = (const float*)d_in[12];
    const float* bs = (const float*)d_in[13];

    char* ws = (char*)d_ws;
    size_t off = 0;
    auto alloc = [&](size_t b) {
        size_t o = off;
        off = (off + b + 255) & ~(size_t)255;
        return o;
    };
    u16* h = (u16*)(ws + alloc((size_t)NN * 128 * 2));
    u16* qv = (u16*)(ws + alloc((size_t)NN * 128 * 2));
    u16* kv = (u16*)(ws + alloc((size_t)NN * 256 * 2));
    u16* skip = (u16*)(ws + alloc((size_t)NN * 128 * 2));
    u16* xb = (u16*)(ws + alloc((size_t)NN * 128 * 2));
    u16* wt1 = (u16*)(ws + alloc((size_t)128 * 1152 * 2));
    u16* wt2 = (u16*)(ws + alloc((size_t)4 * 128 * 128 * 2));
    float* bcat = (float*)(ws + alloc((size_t)512 * 4));
    int* cnt = (int*)(ws + alloc((size_t)NN * 8 * 4));
    int* row_off = (int*)(ws + alloc((size_t)(NN + 1) * 4));
    int* srt = (int*)(ws + alloc((size_t)NN * 8 * 4));
    int* deg_pref = (int*)(ws + alloc((size_t)NN * 4));
    int* blk_sums = (int*)(ws + alloc((size_t)128 * 4));
    int* rank = (int*)(ws + alloc((size_t)EE * 4));
    int* es = (int*)(ws + alloc((size_t)EE * 4));
    (void)ws_size;
    (void)in_sizes;
    (void)n_in;
    (void)out_size;

    prep_all<<<(ZP_N + CX_N + WP_N + 255) / 256, 256, 0, stream>>>(
        x, rw, root, Wq, Wk, Wv, Ws, bq, bk, bv, bs, cnt, xb, wt1, wt2, bcat);

    count_rank<<<(EE + 2047) / 2048, 256, 0, stream>>>(ei, et, cnt, rank);
    scan_phase1<<<SCAN_BLOCKS, 256, 0, stream>>>(cnt, deg_pref, blk_sums);
    scan_phase2<<<1, 128, 0, stream>>>(blk_sums);
    scan_phase3<<<SCAN_BLOCKS, 256, 0, stream>>>(cnt, deg_pref, blk_sums, row_off, srt);
    scatter_kernel<<<(EE + 2047) / 2048, 256, 0, stream>>>(ei, et, srt, rank, es);

    rgcn_gemm<<<(NN + 31) / 32, 256, 0, stream>>>(xb, srt, cnt, es, wt1, rbias, h, NN);
    gemm_qkvs<<<dim3((NN + 63) / 64, 4), 256, 0, stream>>>(h, wt2, bcat, qv, kv, skip, NN);

    attn_kernel<<<(NN + 15) / 16, 256, 0, stream>>>(qv, kv, skip, row_off, es, (float*)d_out);
}

// Round 11
// 247.072 us; speedup vs baseline: 1.0605x; 1.0605x over previous
//
#include <hip/hip_runtime.h>

typedef unsigned short u16;
typedef unsigned int u32;
typedef __attribute__((ext_vector_type(8))) short short8;
typedef __attribute__((ext_vector_type(4))) float f32x4;

#define NN 20000
#define EE 640000
#define SCAN_BLOCKS 80   // 80*256 = 20480 >= NN

__device__ inline u16 f2bf(float f) {
    u32 x = __float_as_uint(f);
    return (u16)((x + 0x7FFFu + ((x >> 16) & 1u)) >> 16);
}
__device__ inline float lo16(u32 w) { return __uint_as_float(w << 16); }
__device__ inline float hi16(u32 w) { return __uint_as_float(w & 0xFFFF0000u); }
__device__ inline u32 packbf(float a, float b) { return ((u32)f2bf(b) << 16) | (u32)f2bf(a); }

// ---------------- fused prep: zero cnt + cast x->bf16 + weight transpose/cast ----------------
#define ZP_N (NN * 8)
#define CX_N (NN * 32)
#define WP_N (128 * 1152 + 4 * 128 * 128 + 512)
__global__ __launch_bounds__(256) void prep_all(const float* __restrict__ x,
                                                const float* rw, const float* root,
                                                const float* Wq, const float* Wk,
                                                const float* Wv, const float* Ws,
                                                const float* bq, const float* bk,
                                                const float* bv, const float* bs,
                                                int* __restrict__ cnt, u16* __restrict__ xb,
                                                u16* wt1, u16* wt2, float* bcat) {
    int idx = blockIdx.x * 256 + threadIdx.x;
    if (idx < ZP_N) {
        cnt[idx] = 0;
        return;
    }
    idx -= ZP_N;
    if (idx < CX_N) {
        float4 v = *(const float4*)(x + (size_t)idx * 4);
        uint2 o;
        o.x = packbf(v.x, v.y);
        o.y = packbf(v.z, v.w);
        *(uint2*)(xb + (size_t)idx * 4) = o;
        return;
    }
    idx -= CX_N;
    const int S1 = 128 * 1152, S2 = 4 * 128 * 128;
    if (idx < S1) {
        int o = idx / 1152, k = idx - o * 1152;
        float v = (k < 1024) ? rw[k * 128 + o] : root[(k - 1024) * 128 + o];
        wt1[idx] = f2bf(v);
    } else if (idx < S1 + S2) {
        int j = idx - S1;
        int y = j >> 14, rem = j & 16383, o = rem >> 7, i = rem & 127;
        const float* W = (y == 0) ? Wq : (y == 1) ? Wk : (y == 2) ? Wv : Ws;
        wt2[j] = f2bf(W[i * 128 + o]);
    } else if (idx < S1 + S2 + 512) {
        int j = idx - (S1 + S2);
        int y = j >> 7, c = j & 127;
        const float* b = (y == 0) ? bq : (y == 1) ? bk : (y == 2) ? bv : bs;
        bcat[j] = b[c];
    }
}

// ---------------- CSR build: one atomic per edge, 8 edges/thread ----------------
__global__ void count_rank(const int* __restrict__ ei, const int* __restrict__ et,
                           int* __restrict__ cnt, int* __restrict__ rank) {
    int base = blockIdx.x * 2048 + threadIdx.x;
#pragma unroll
    for (int j = 0; j < 8; j++) {
        int e = base + j * 256;
        if (e < EE) {
            int dst = ei[EE + e];
            int r = et[e];
            rank[e] = atomicAdd(&cnt[dst * 8 + r], 1);
        }
    }
}

// ---------------- parallel scan (2 kernels) ----------------
// phase1: per-node degree, intra-block inclusive scan, block totals
__global__ __launch_bounds__(256) void scan_phase1(const int* __restrict__ cnt,
                                                   int* __restrict__ deg_pref,
                                                   int* __restrict__ blk_sums) {
    __shared__ int lds[256];
    int t = threadIdx.x;
    int n = blockIdx.x * 256 + t;
    int d = 0;
    if (n < NN) {
        int4 c0 = *(const int4*)(cnt + n * 8);
        int4 c1 = *(const int4*)(cnt + n * 8 + 4);
        d = c0.x + c0.y + c0.z + c0.w + c1.x + c1.y + c1.z + c1.w;
    }
    lds[t] = d;
    __syncthreads();
    for (int o = 1; o < 256; o <<= 1) {
        int v = (t >= o) ? lds[t - o] : 0;
        __syncthreads();
        lds[t] += v;
        __syncthreads();
    }
    if (n < NN) deg_pref[n] = lds[t];
    if (t == 255) blk_sums[blockIdx.x] = lds[255];
}

// phase3: each block redundantly scans the 80 block sums, then emits row_off + srt
__global__ __launch_bounds__(256) void scan_phase3(const int* __restrict__ cnt,
                                                   const int* __restrict__ deg_pref,
                                                   const int* __restrict__ blk_sums,
                                                   int* __restrict__ row_off,
                                                   int* __restrict__ srt) {
    __shared__ int bs_lds[128];
    int t = threadIdx.x;
    if (t < 128) {
        int v = (t < SCAN_BLOCKS) ? blk_sums[t] : 0;
        bs_lds[t] = v;
    }
    __syncthreads();
    if (t < 128) {
        for (int o = 1; o < 128; o <<= 1) {
            int a = (t >= o) ? bs_lds[t - o] : 0;
            __syncthreads();
            bs_lds[t] += a;
            __syncthreads();
        }
    } else {
        for (int o = 1; o < 128; o <<= 1) {
            __syncthreads();
            __syncthreads();
        }
    }
    int blk_excl = (blockIdx.x > 0) ? bs_lds[blockIdx.x - 1] : 0;
    int n = blockIdx.x * 256 + t;
    if (n >= NN) return;
    int4 c0 = *(const int4*)(cnt + n * 8);
    int4 c1 = *(const int4*)(cnt + n * 8 + 4);
    int deg = c0.x + c0.y + c0.z + c0.w + c1.x + c1.y + c1.z + c1.w;
    int start = blk_excl + deg_pref[n] - deg;   // exclusive global prefix
    row_off[n] = start;
    int sub = start;
    int o[8];
    o[0] = sub; sub += c0.x;
    o[1] = sub; sub += c0.y;
    o[2] = sub; sub += c0.z;
    o[3] = sub; sub += c0.w;
    o[4] = sub; sub += c1.x;
    o[5] = sub; sub += c1.y;
    o[6] = sub; sub += c1.z;
    o[7] = sub; sub += c1.w;
    *(int4*)(srt + n * 8) = make_int4(o[0], o[1], o[2], o[3]);
    *(int4*)(srt + n * 8 + 4) = make_int4(o[4], o[5], o[6], o[7]);
    if (n == NN - 1) row_off[NN] = sub;
}

// atomic-free scatter, 8 edges/thread
__global__ void scatter_kernel(const int* __restrict__ ei, const int* __restrict__ et,
                               const int* __restrict__ srt, const int* __restrict__ rank,
                               int* __restrict__ es) {
    int base = blockIdx.x * 2048 + threadIdx.x;
#pragma unroll
    for (int j = 0; j < 8; j++) {
        int e = base + j * 256;
        if (e < EE) {
            int dst = ei[EE + e];
            int src = ei[e];
            int r = et[e];
            es[srt[dst * 8 + r] + rank[e]] = src;
        }
    }
}

// ---------------- RGCN pre-aggregation: 16-lane group per (node,relation) ----------------
// slot 0..7 = relation mean-aggregate; slot 8 = copy x row into tail (root fused into GEMM)
__global__ __launch_bounds__(256) void rgcn_agg(const u16* __restrict__ xb,
                                                const int* __restrict__ srt,
                                                const int* __restrict__ cnt,
                                                const int* __restrict__ es,
                                                u16* __restrict__ pre) {
    int gid = blockIdx.x * 16 + (threadIdx.x >> 4);
    int lane = threadIdx.x & 15;     // 8 dims/lane
    if (gid >= NN * 9) return;
    int node = gid / 9;
    int slot = gid - node * 9;
    long prebase = (long)node * 1152;
    if (slot == 8) {
        uint4 xv = *(const uint4*)(xb + (long)node * 128 + lane * 8);
        *(uint4*)(pre + prebase + 1024 + lane * 8) = xv;
        return;
    }
    int c = cnt[node * 8 + slot];
    int p0 = srt[node * 8 + slot];
    float inv = 1.0f / (float)(c > 1 ? c : 1);
    float a0 = 0.f, a1 = 0.f, a2 = 0.f, a3 = 0.f, a4 = 0.f, a5 = 0.f, a6 = 0.f, a7 = 0.f;
    int i = 0;
    for (; i + 4 <= c; i += 4) {
        int s0 = es[p0 + i], s1 = es[p0 + i + 1], s2 = es[p0 + i + 2], s3 = es[p0 + i + 3];
        uint4 w0 = *(const uint4*)(xb + (long)s0 * 128 + lane * 8);
        uint4 w1 = *(const uint4*)(xb + (long)s1 * 128 + lane * 8);
        uint4 w2 = *(const uint4*)(xb + (long)s2 * 128 + lane * 8);
        uint4 w3 = *(const uint4*)(xb + (long)s3 * 128 + lane * 8);
        a0 += (lo16(w0.x) + lo16(w1.x)) + (lo16(w2.x) + lo16(w3.x));
        a1 += (hi16(w0.x) + hi16(w1.x)) + (hi16(w2.x) + hi16(w3.x));
        a2 += (lo16(w0.y) + lo16(w1.y)) + (lo16(w2.y) + lo16(w3.y));
        a3 += (hi16(w0.y) + hi16(w1.y)) + (hi16(w2.y) + hi16(w3.y));
        a4 += (lo16(w0.z) + lo16(w1.z)) + (lo16(w2.z) + lo16(w3.z));
        a5 += (hi16(w0.z) + hi16(w1.z)) + (hi16(w2.z) + hi16(w3.z));
        a6 += (lo16(w0.w) + lo16(w1.w)) + (lo16(w2.w) + lo16(w3.w));
        a7 += (hi16(w0.w) + hi16(w1.w)) + (hi16(w2.w) + hi16(w3.w));
    }
    for (; i < c; i++) {
        int s = es[p0 + i];
        uint4 w = *(const uint4*)(xb + (long)s * 128 + lane * 8);
        a0 += lo16(w.x); a1 += hi16(w.x); a2 += lo16(w.y); a3 += hi16(w.y);
        a4 += lo16(w.z); a5 += hi16(w.z); a6 += lo16(w.w); a7 += hi16(w.w);
    }
    uint4 ow;
    ow.x = packbf(a0 * inv, a1 * inv);
    ow.y = packbf(a2 * inv, a3 * inv);
    ow.z = packbf(a4 * inv, a5 * inv);
    ow.w = packbf(a6 * inv, a7 * inv);
    *(uint4*)(pre + prebase + slot * 128 + lane * 8) = ow;
}

// ---------------- GEMM1: BM=32 tiles, K=1152, relu.  C[rows x 128] = A*Bt^T + bias ----------------
__global__ __launch_bounds__(256) void gemm_bm32(const u16* __restrict__ A,
                                                 const u16* __restrict__ Bt,
                                                 const float* __restrict__ bias,
                                                 u16* __restrict__ C, int rows) {
    __shared__ u16 As[32 * 136];
    __shared__ u16 Bs[128 * 136];
    int tid = threadIdx.x;
    int w = tid >> 6;
    int lane = tid & 63;
    int quad = lane >> 4;
    int ml = lane & 15;
    int mt = w & 1;
    int nq = w >> 1;
    int block_m = blockIdx.x * 32;

    f32x4 acc[4];
#pragma unroll
    for (int i = 0; i < 4; i++) acc[i] = (f32x4){0.f, 0.f, 0.f, 0.f};

    int rbase = tid >> 4;
    int cb = (tid & 15) * 8;

    for (int kb = 0; kb < 1152; kb += 128) {
#pragma unroll
        for (int rep = 0; rep < 2; rep++) {
            int r = rbase + rep * 16;
            int gr = block_m + r;
            short8 val = {};
            if (gr < rows) val = *(const short8*)(A + (long)gr * 1152 + kb + cb);
            *(short8*)(As + r * 136 + cb) = val;
        }
#pragma unroll
        for (int rep = 0; rep < 8; rep++) {
            int r = rbase + rep * 16;
            short8 val = *(const short8*)(Bt + (long)r * 1152 + kb + cb);
            *(short8*)(Bs + r * 136 + cb) = val;
        }
        __syncthreads();
#pragma unroll
        for (int ks = 0; ks < 4; ks++) {
            short8 af = *(const short8*)(As + (mt * 16 + ml) * 136 + ks * 32 + quad * 8);
#pragma unroll
            for (int nt = 0; nt < 4; nt++) {
                short8 bfr = *(const short8*)(Bs + (nq * 64 + nt * 16 + ml) * 136 + ks * 32 + quad * 8);
                acc[nt] = __builtin_amdgcn_mfma_f32_16x16x32_bf16(af, bfr, acc[nt], 0, 0, 0);
            }
        }
        __syncthreads();
    }
#pragma unroll
    for (int nt = 0; nt < 4; nt++) {
        int col = nq * 64 + nt * 16 + ml;
        float bv = bias[col];
#pragma unroll
        for (int i = 0; i < 4; i++) {
            int gr = block_m + mt * 16 + quad * 4 + i;
            if (gr < rows) {
                float vv = fmaxf(acc[nt][i] + bv, 0.f);
                C[(long)gr * 128 + col] = f2bf(vv);
            }
        }
    }
}

// ---------------- GEMM2 (q / kv-interleaved / skip): BM=64, K=128 ----------------
__global__ __launch_bounds__(256) void gemm_qkvs(const u16* __restrict__ A,
                                                 const u16* __restrict__ Bt,
                                                 const float* __restrict__ bias,
                                                 u16* __restrict__ Cq, u16* __restrict__ Ckv,
                                                 u16* __restrict__ Cs, int rows) {
    int y = blockIdx.y;
    Bt += (long)y * 128 * 128;
    bias += y * 128;
    u16* C;
    int ldc;
    if (y == 0) { C = Cq; ldc = 128; }
    else if (y == 1) { C = Ckv; ldc = 256; }
    else if (y == 2) { C = Ckv + 128; ldc = 256; }
    else { C = Cs; ldc = 128; }

    __shared__ u16 As[64 * 136];
    __shared__ u16 Bs[128 * 136];
    int tid = threadIdx.x;
    int w = tid >> 6;
    int lane = tid & 63;
    int quad = lane >> 4;
    int ml = lane & 15;
    int block_m = blockIdx.x * 64;

    f32x4 acc[8];
#pragma unroll
    for (int i = 0; i < 8; i++) acc[i] = (f32x4){0.f, 0.f, 0.f, 0.f};

    int rbase = tid >> 4;
    int cb = (tid & 15) * 8;

#pragma unroll
    for (int rep = 0; rep < 4; rep++) {
        int r = rbase + rep * 16;
        int gr = block_m + r;
        short8 val = {};
        if (gr < rows) val = *(const short8*)(A + (long)gr * 128 + cb);
        *(short8*)(As + r * 136 + cb) = val;
    }
#pragma unroll
    for (int rep = 0; rep < 8; rep++) {
        int r = rbase + rep * 16;
        short8 val = *(const short8*)(Bt + (long)r * 128 + cb);
        *(short8*)(Bs + r * 136 + cb) = val;
    }
    __syncthreads();
#pragma unroll
    for (int ks = 0; ks < 4; ks++) {
        short8 af = *(const short8*)(As + (w * 16 + ml) * 136 + ks * 32 + quad * 8);
#pragma unroll
        for (int nt = 0; nt < 8; nt++) {
            short8 bfr = *(const short8*)(Bs + (nt * 16 + ml) * 136 + ks * 32 + quad * 8);
            acc[nt] = __builtin_amdgcn_mfma_f32_16x16x32_bf16(af, bfr, acc[nt], 0, 0, 0);
        }
    }
#pragma unroll
    for (int nt = 0; nt < 8; nt++) {
        int col = nt * 16 + ml;
        float bv = bias[col];
#pragma unroll
        for (int i = 0; i < 4; i++) {
            int gr = block_m + w * 16 + quad * 4 + i;
            if (gr < rows) {
                C[(long)gr * ldc + col] = f2bf(acc[nt][i] + bv);
            }
        }
    }
}

// ---------------- attention: 16-lane/node, direct-exp softmax, fused KV ----------------
__global__ __launch_bounds__(256) void attn_kernel(const u16* __restrict__ q,
                                                   const u16* __restrict__ kv,
                                                   const u16* __restrict__ skip,
                                                   const int* __restrict__ row_off,
                                                   const int* __restrict__ es,
                                                   float* __restrict__ out) {
    int node = blockIdx.x * 16 + (threadIdx.x >> 4);
    int lane = threadIdx.x & 15;     // 8 dims/lane
    if (node >= NN) return;
    int p0 = row_off[node], p1 = row_off[node + 1];
    uint4 qw = *(const uint4*)(q + (long)node * 128 + lane * 8);
    float q0 = lo16(qw.x), q1 = hi16(qw.x), q2 = lo16(qw.y), q3 = hi16(qw.y);
    float q4 = lo16(qw.z), q5 = hi16(qw.z), q6 = lo16(qw.w), q7 = hi16(qw.w);
    const float SC = 0.08838834764831845f;  // 1/sqrt(128)
    float l = 0.f;
    float a0 = 0.f, a1 = 0.f, a2 = 0.f, a3 = 0.f, a4 = 0.f, a5 = 0.f, a6 = 0.f, a7 = 0.f;
    int p = p0;
    for (; p + 4 <= p1; p += 4) {
        const u16* b0 = kv + (long)es[p] * 256 + lane * 8;
        const u16* b1 = kv + (long)es[p + 1] * 256 + lane * 8;
        const u16* b2 = kv + (long)es[p + 2] * 256 + lane * 8;
        const u16* b3 = kv + (long)es[p + 3] * 256 + lane * 8;
        uint4 k0 = *(const uint4*)b0;
        uint4 k1 = *(const uint4*)b1;
        uint4 k2 = *(const uint4*)b2;
        uint4 k3 = *(const uint4*)b3;
        uint4 v0 = *(const uint4*)(b0 + 128);
        uint4 v1 = *(const uint4*)(b1 + 128);
        uint4 v2 = *(const uint4*)(b2 + 128);
        uint4 v3 = *(const uint4*)(b3 + 128);
        float t0 = q0 * lo16(k0.x) + q1 * hi16(k0.x) + q2 * lo16(k0.y) + q3 * hi16(k0.y) +
                   q4 * lo16(k0.z) + q5 * hi16(k0.z) + q6 * lo16(k0.w) + q7 * hi16(k0.w);
        float t1 = q0 * lo16(k1.x) + q1 * hi16(k1.x) + q2 * lo16(k1.y) + q3 * hi16(k1.y) +
                   q4 * lo16(k1.z) + q5 * hi16(k1.z) + q6 * lo16(k1.w) + q7 * hi16(k1.w);
        float t2 = q0 * lo16(k2.x) + q1 * hi16(k2.x) + q2 * lo16(k2.y) + q3 * hi16(k2.y) +
                   q4 * lo16(k2.z) + q5 * hi16(k2.z) + q6 * lo16(k2.w) + q7 * hi16(k2.w);
        float t3 = q0 * lo16(k3.x) + q1 * hi16(k3.x) + q2 * lo16(k3.y) + q3 * hi16(k3.y) +
                   q4 * lo16(k3.z) + q5 * hi16(k3.z) + q6 * lo16(k3.w) + q7 * hi16(k3.w);
#pragma unroll
        for (int off = 8; off >= 1; off >>= 1) {
            t0 += __shfl_xor(t0, off, 16);
            t1 += __shfl_xor(t1, off, 16);
            t2 += __shfl_xor(t2, off, 16);
            t3 += __shfl_xor(t3, off, 16);
        }
        float w0 = __expf(fminf(t0 * SC, 70.f));
        float w1 = __expf(fminf(t1 * SC, 70.f));
        float w2 = __expf(fminf(t2 * SC, 70.f));
        float w3 = __expf(fminf(t3 * SC, 70.f));
        l += (w0 + w1) + (w2 + w3);
        a0 += w0 * lo16(v0.x) + w1 * lo16(v1.x) + w2 * lo16(v2.x) + w3 * lo16(v3.x);
        a1 += w0 * hi16(v0.x) + w1 * hi16(v1.x) + w2 * hi16(v2.x) + w3 * hi16(v3.x);
        a2 += w0 * lo16(v0.y) + w1 * lo16(v1.y) + w2 * lo16(v2.y) + w3 * lo16(v3.y);
        a3 += w0 * hi16(v0.y) + w1 * hi16(v1.y) + w2 * hi16(v2.y) + w3 * hi16(v3.y);
        a4 += w0 * lo16(v0.z) + w1 * lo16(v1.z) + w2 * lo16(v2.z) + w3 * lo16(v3.z);
        a5 += w0 * hi16(v0.z) + w1 * hi16(v1.z) + w2 * hi16(v2.z) + w3 * hi16(v3.z);
        a6 += w0 * lo16(v0.w) + w1 * lo16(v1.w) + w2 * lo16(v2.w) + w3 * lo16(v3.w);
        a7 += w0 * hi16(v0.w) + w1 * hi16(v1.w) + w2 * hi16(v2.w) + w3 * hi16(v3.w);
    }
    for (; p < p1; p++) {
        const u16* b = kv + (long)es[p] * 256 + lane * 8;
        uint4 kw = *(const uint4*)b;
        uint4 vw = *(const uint4*)(b + 128);
        float t = q0 * lo16(kw.x) + q1 * hi16(kw.x) + q2 * lo16(kw.y) + q3 * hi16(kw.y) +
                  q4 * lo16(kw.z) + q5 * hi16(kw.z) + q6 * lo16(kw.w) + q7 * hi16(kw.w);
#pragma unroll
        for (int off = 8; off >= 1; off >>= 1) t += __shfl_xor(t, off, 16);
        float w = __expf(fminf(t * SC, 70.f));
        l += w;
        a0 += w * lo16(vw.x);
        a1 += w * hi16(vw.x);
        a2 += w * lo16(vw.y);
        a3 += w * hi16(vw.y);
        a4 += w * lo16(vw.z);
        a5 += w * hi16(vw.z);
        a6 += w * lo16(vw.w);
        a7 += w * hi16(vw.w);
    }
    float invl = (l > 0.f) ? 1.0f / l : 0.f;
    uint4 sw = *(const uint4*)(skip + (long)node * 128 + lane * 8);
    float4 oa, ob;
    oa.x = fmaxf(a0 * invl + lo16(sw.x), 0.f);
    oa.y = fmaxf(a1 * invl + hi16(sw.x), 0.f);
    oa.z = fmaxf(a2 * invl + lo16(sw.y), 0.f);
    oa.w = fmaxf(a3 * invl + hi16(sw.y), 0.f);
    ob.x = fmaxf(a4 * invl + lo16(sw.z), 0.f);
    ob.y = fmaxf(a5 * invl + hi16(sw.z), 0.f);
    ob.z = fmaxf(a6 * invl + lo16(sw.w), 0.f);
    ob.w = fmaxf(a7 * invl + hi16(sw.w), 0.f);
    *(float4*)(out + (long)node * 128 + lane * 8) = oa;
    *(float4*)(out + (long)node * 128 + lane * 8 + 4) = ob;
}

extern "C" void kernel_launch(void* const* d_in, const int* in_sizes, int n_in,
                              void* d_out, int out_size, void* d_ws, size_t ws_size,
                              hipStream_t stream) {
    const float* x = (const float*)d_in[0];
    const int* ei = (const int*)d_in[1];
    const int* et = (const int*)d_in[2];
    const float* rw = (const float*)d_in[3];
    const float* root = (const float*)d_in[4];
    const float* rbias = (const float*)d_in[5];
    const float* Wq = (const float*)d_in[6];
    const float* bq = (const float*)d_in[7];
    const float* Wk = (const float*)d_in[8];
    const float* bk = (const float*)d_in[9];
    const float* Wv = (const float*)d_in[10];
    const float* bv = (const float*)d_in[11];
    const float* Ws = (const float*)d_in[12];
    const float* bs = (const float*)d_in[13];

    char* ws = (char*)d_ws;
    size_t off = 0;
    auto alloc = [&](size_t b) {
        size_t o = off;
        off = (off + b + 255) & ~(size_t)255;
        return o;
    };
    u16* pre = (u16*)(ws + alloc((size_t)NN * 1152 * 2));
    u16* h = (u16*)(ws + alloc((size_t)NN * 128 * 2));
    u16* qv = (u16*)(ws + alloc((size_t)NN * 128 * 2));
    u16* kv = (u16*)(ws + alloc((size_t)NN * 256 * 2));
    u16* skip = (u16*)(ws + alloc((size_t)NN * 128 * 2));
    u16* xb = (u16*)(ws + alloc((size_t)NN * 128 * 2));
    u16* wt1 = (u16*)(ws + alloc((size_t)128 * 1152 * 2));
    u16* wt2 = (u16*)(ws + alloc((size_t)4 * 128 * 128 * 2));
    float* bcat = (float*)(ws + alloc((size_t)512 * 4));
    int* cnt = (int*)(ws + alloc((size_t)NN * 8 * 4));
    int* row_off = (int*)(ws + alloc((size_t)(NN + 1) * 4));
    int* srt = (int*)(ws + alloc((size_t)NN * 8 * 4));
    int* deg_pref = (int*)(ws + alloc((size_t)NN * 4));
    int* blk_sums = (int*)(ws + alloc((size_t)128 * 4));
    int* rank = (int*)(ws + alloc((size_t)EE * 4));
    int* es = (int*)(ws + alloc((size_t)EE * 4));
    (void)ws_size;
    (void)in_sizes;
    (void)n_in;
    (void)out_size;

    prep_all<<<(ZP_N + CX_N + WP_N + 255) / 256, 256, 0, stream>>>(
        x, rw, root, Wq, Wk, Wv, Ws, bq, bk, bv, bs, cnt, xb, wt1, wt2, bcat);

    count_rank<<<(EE + 2047) / 2048, 256, 0, stream>>>(ei, et, cnt, rank);
    scan_phase1<<<SCAN_BLOCKS, 256, 0, stream>>>(cnt, deg_pref, blk_sums);
    scan_phase3<<<SCAN_BLOCKS, 256, 0, stream>>>(cnt, deg_pref, blk_sums, row_off, srt);
    scatter_kernel<<<(EE + 2047) / 2048, 256, 0, stream>>>(ei, et, srt, rank, es);

    rgcn_agg<<<(NN * 9 + 15) / 16, 256, 0, stream>>>(xb, srt, cnt, es, pre);

    gemm_bm32<<<(NN + 31) / 32, 256, 0, stream>>>(pre, wt1, rbias, h, NN);
    gemm_qkvs<<<dim3((NN + 63) / 64, 4), 256, 0, stream>>>(h, wt2, bcat, qv, kv, skip, NN);

    attn_kernel<<<(NN + 15) / 16, 256, 0, stream>>>(qv, kv, skip, row_off, es, (float*)d_out);
}

// Round 12
// 235.270 us; speedup vs baseline: 1.1137x; 1.0502x over previous
//
#include <hip/hip_runtime.h>

typedef unsigned short u16;
typedef unsigned int u32;
typedef __attribute__((ext_vector_type(8))) short short8;
typedef __attribute__((ext_vector_type(4))) float f32x4;

#define NN 20000
#define EE 640000
#define SCAN_BLOCKS 80   // 80*256 = 20480 >= NN

__device__ inline u16 f2bf(float f) {
    u32 x = __float_as_uint(f);
    return (u16)((x + 0x7FFFu + ((x >> 16) & 1u)) >> 16);
}
__device__ inline float lo16(u32 w) { return __uint_as_float(w << 16); }
__device__ inline float hi16(u32 w) { return __uint_as_float(w & 0xFFFF0000u); }
__device__ inline u32 packbf(float a, float b) { return ((u32)f2bf(b) << 16) | (u32)f2bf(a); }

// ---------------- fused prep: zero cnt + cast x->bf16 + weight transpose/cast ----------------
#define ZP_N (NN * 8)
#define CX_N (NN * 32)
#define WP_N (128 * 1152 + 4 * 128 * 128 + 512)
__global__ __launch_bounds__(256) void prep_all(const float* __restrict__ x,
                                                const float* rw, const float* root,
                                                const float* Wq, const float* Wk,
                                                const float* Wv, const float* Ws,
                                                const float* bq, const float* bk,
                                                const float* bv, const float* bs,
                                                int* __restrict__ cnt, u16* __restrict__ xb,
                                                u16* wt1, u16* wt2, float* bcat) {
    int idx = blockIdx.x * 256 + threadIdx.x;
    if (idx < ZP_N) {
        cnt[idx] = 0;
        return;
    }
    idx -= ZP_N;
    if (idx < CX_N) {
        float4 v = *(const float4*)(x + (size_t)idx * 4);
        uint2 o;
        o.x = packbf(v.x, v.y);
        o.y = packbf(v.z, v.w);
        *(uint2*)(xb + (size_t)idx * 4) = o;
        return;
    }
    idx -= CX_N;
    const int S1 = 128 * 1152, S2 = 4 * 128 * 128;
    if (idx < S1) {
        int o = idx / 1152, k = idx - o * 1152;
        float v = (k < 1024) ? rw[k * 128 + o] : root[(k - 1024) * 128 + o];
        wt1[idx] = f2bf(v);
    } else if (idx < S1 + S2) {
        int j = idx - S1;
        int y = j >> 14, rem = j & 16383, o = rem >> 7, i = rem & 127;
        const float* W = (y == 0) ? Wq : (y == 1) ? Wk : (y == 2) ? Wv : Ws;
        wt2[j] = f2bf(W[i * 128 + o]);
    } else if (idx < S1 + S2 + 512) {
        int j = idx - (S1 + S2);
        int y = j >> 7, c = j & 127;
        const float* b = (y == 0) ? bq : (y == 1) ? bk : (y == 2) ? bv : bs;
        bcat[j] = b[c];
    }
}

// ---------------- CSR build: one atomic per edge, 8 edges/thread ----------------
__global__ void count_rank(const int* __restrict__ ei, const int* __restrict__ et,
                           int* __restrict__ cnt, int* __restrict__ rank) {
    int base = blockIdx.x * 2048 + threadIdx.x;
#pragma unroll
    for (int j = 0; j < 8; j++) {
        int e = base + j * 256;
        if (e < EE) {
            int dst = ei[EE + e];
            int r = et[e];
            rank[e] = atomicAdd(&cnt[dst * 8 + r], 1);
        }
    }
}

// ---------------- parallel scan (2 kernels) ----------------
__global__ __launch_bounds__(256) void scan_phase1(const int* __restrict__ cnt,
                                                   int* __restrict__ deg_pref,
                                                   int* __restrict__ blk_sums) {
    __shared__ int lds[256];
    int t = threadIdx.x;
    int n = blockIdx.x * 256 + t;
    int d = 0;
    if (n < NN) {
        int4 c0 = *(const int4*)(cnt + n * 8);
        int4 c1 = *(const int4*)(cnt + n * 8 + 4);
        d = c0.x + c0.y + c0.z + c0.w + c1.x + c1.y + c1.z + c1.w;
    }
    lds[t] = d;
    __syncthreads();
    for (int o = 1; o < 256; o <<= 1) {
        int v = (t >= o) ? lds[t - o] : 0;
        __syncthreads();
        lds[t] += v;
        __syncthreads();
    }
    if (n < NN) deg_pref[n] = lds[t];
    if (t == 255) blk_sums[blockIdx.x] = lds[255];
}

__global__ __launch_bounds__(256) void scan_phase3(const int* __restrict__ cnt,
                                                   const int* __restrict__ deg_pref,
                                                   const int* __restrict__ blk_sums,
                                                   int* __restrict__ row_off,
                                                   int* __restrict__ srt) {
    __shared__ int bs_lds[128];
    int t = threadIdx.x;
    if (t < 128) {
        int v = (t < SCAN_BLOCKS) ? blk_sums[t] : 0;
        bs_lds[t] = v;
    }
    __syncthreads();
    if (t < 128) {
        for (int o = 1; o < 128; o <<= 1) {
            int a = (t >= o) ? bs_lds[t - o] : 0;
            __syncthreads();
            bs_lds[t] += a;
            __syncthreads();
        }
    } else {
        for (int o = 1; o < 128; o <<= 1) {
            __syncthreads();
            __syncthreads();
        }
    }
    int blk_excl = (blockIdx.x > 0) ? bs_lds[blockIdx.x - 1] : 0;
    int n = blockIdx.x * 256 + t;
    if (n >= NN) return;
    int4 c0 = *(const int4*)(cnt + n * 8);
    int4 c1 = *(const int4*)(cnt + n * 8 + 4);
    int deg = c0.x + c0.y + c0.z + c0.w + c1.x + c1.y + c1.z + c1.w;
    int start = blk_excl + deg_pref[n] - deg;   // exclusive global prefix
    row_off[n] = start;
    int sub = start;
    int o[8];
    o[0] = sub; sub += c0.x;
    o[1] = sub; sub += c0.y;
    o[2] = sub; sub += c0.z;
    o[3] = sub; sub += c0.w;
    o[4] = sub; sub += c1.x;
    o[5] = sub; sub += c1.y;
    o[6] = sub; sub += c1.z;
    o[7] = sub; sub += c1.w;
    *(int4*)(srt + n * 8) = make_int4(o[0], o[1], o[2], o[3]);
    *(int4*)(srt + n * 8 + 4) = make_int4(o[4], o[5], o[6], o[7]);
    if (n == NN - 1) row_off[NN] = sub;
}

// atomic-free scatter, 8 edges/thread
__global__ void scatter_kernel(const int* __restrict__ ei, const int* __restrict__ et,
                               const int* __restrict__ srt, const int* __restrict__ rank,
                               int* __restrict__ es) {
    int base = blockIdx.x * 2048 + threadIdx.x;
#pragma unroll
    for (int j = 0; j < 8; j++) {
        int e = base + j * 256;
        if (e < EE) {
            int dst = ei[EE + e];
            int src = ei[e];
            int r = et[e];
            es[srt[dst * 8 + r] + rank[e]] = src;
        }
    }
}

// ---------------- RGCN pre-aggregation: 16-lane group per (node,relation) ----------------
__global__ __launch_bounds__(256) void rgcn_agg(const u16* __restrict__ xb,
                                                const int* __restrict__ srt,
                                                const int* __restrict__ cnt,
                                                const int* __restrict__ es,
                                                u16* __restrict__ pre) {
    int gid = blockIdx.x * 16 + (threadIdx.x >> 4);
    int lane = threadIdx.x & 15;     // 8 dims/lane
    if (gid >= NN * 9) return;
    int node = gid / 9;
    int slot = gid - node * 9;
    long prebase = (long)node * 1152;
    if (slot == 8) {
        uint4 xv = *(const uint4*)(xb + (long)node * 128 + lane * 8);
        *(uint4*)(pre + prebase + 1024 + lane * 8) = xv;
        return;
    }
    int c = cnt[node * 8 + slot];
    int p0 = srt[node * 8 + slot];
    float inv = 1.0f / (float)(c > 1 ? c : 1);
    float a0 = 0.f, a1 = 0.f, a2 = 0.f, a3 = 0.f, a4 = 0.f, a5 = 0.f, a6 = 0.f, a7 = 0.f;
    int i = 0;
    for (; i + 4 <= c; i += 4) {
        int s0 = es[p0 + i], s1 = es[p0 + i + 1], s2 = es[p0 + i + 2], s3 = es[p0 + i + 3];
        uint4 w0 = *(const uint4*)(xb + (long)s0 * 128 + lane * 8);
        uint4 w1 = *(const uint4*)(xb + (long)s1 * 128 + lane * 8);
        uint4 w2 = *(const uint4*)(xb + (long)s2 * 128 + lane * 8);
        uint4 w3 = *(const uint4*)(xb + (long)s3 * 128 + lane * 8);
        a0 += (lo16(w0.x) + lo16(w1.x)) + (lo16(w2.x) + lo16(w3.x));
        a1 += (hi16(w0.x) + hi16(w1.x)) + (hi16(w2.x) + hi16(w3.x));
        a2 += (lo16(w0.y) + lo16(w1.y)) + (lo16(w2.y) + lo16(w3.y));
        a3 += (hi16(w0.y) + hi16(w1.y)) + (hi16(w2.y) + hi16(w3.y));
        a4 += (lo16(w0.z) + lo16(w1.z)) + (lo16(w2.z) + lo16(w3.z));
        a5 += (hi16(w0.z) + hi16(w1.z)) + (hi16(w2.z) + hi16(w3.z));
        a6 += (lo16(w0.w) + lo16(w1.w)) + (lo16(w2.w) + lo16(w3.w));
        a7 += (hi16(w0.w) + hi16(w1.w)) + (hi16(w2.w) + hi16(w3.w));
    }
    for (; i < c; i++) {
        int s = es[p0 + i];
        uint4 w = *(const uint4*)(xb + (long)s * 128 + lane * 8);
        a0 += lo16(w.x); a1 += hi16(w.x); a2 += lo16(w.y); a3 += hi16(w.y);
        a4 += lo16(w.z); a5 += hi16(w.z); a6 += lo16(w.w); a7 += hi16(w.w);
    }
    uint4 ow;
    ow.x = packbf(a0 * inv, a1 * inv);
    ow.y = packbf(a2 * inv, a3 * inv);
    ow.z = packbf(a4 * inv, a5 * inv);
    ow.w = packbf(a6 * inv, a7 * inv);
    *(uint4*)(pre + prebase + slot * 128 + lane * 8) = ow;
}

// ---------------- fused GEMM: h=relu(pre@W1+b1) kept in LDS, then q/kv/skip = h@Wy+by ----------------
// BM=32; 20000 = 625 * 32 exactly.
__global__ __launch_bounds__(256) void gemm_fused(const u16* __restrict__ A,
                                                  const u16* __restrict__ Bt1,
                                                  const float* __restrict__ bias1,
                                                  const u16* __restrict__ Wt2,
                                                  const float* __restrict__ bcat,
                                                  u16* __restrict__ Cq, u16* __restrict__ Ckv,
                                                  u16* __restrict__ Cs) {
    __shared__ u16 As[32 * 136];
    __shared__ u16 Bs[128 * 136];
    int tid = threadIdx.x;
    int w = tid >> 6;
    int lane = tid & 63;
    int quad = lane >> 4;
    int ml = lane & 15;
    int mt = w & 1;          // m-tile (0..1)
    int nq = w >> 1;         // n-quarter (0..1)
    int block_m = blockIdx.x * 32;

    f32x4 acc[4];
#pragma unroll
    for (int i = 0; i < 4; i++) acc[i] = (f32x4){0.f, 0.f, 0.f, 0.f};

    int rbase = tid >> 4;
    int cb = (tid & 15) * 8;

    // ---- stage 1: h-tile = relu(pre-tile @ wt1^T + b1) ----
    for (int kb = 0; kb < 1152; kb += 128) {
#pragma unroll
        for (int rep = 0; rep < 2; rep++) {
            int r = rbase + rep * 16;
            short8 val = *(const short8*)(A + (long)(block_m + r) * 1152 + kb + cb);
            *(short8*)(As + r * 136 + cb) = val;
        }
#pragma unroll
        for (int rep = 0; rep < 8; rep++) {
            int r = rbase + rep * 16;
            short8 val = *(const short8*)(Bt1 + (long)r * 1152 + kb + cb);
            *(short8*)(Bs + r * 136 + cb) = val;
        }
        __syncthreads();
#pragma unroll
        for (int ks = 0; ks < 4; ks++) {
            short8 af = *(const short8*)(As + (mt * 16 + ml) * 136 + ks * 32 + quad * 8);
#pragma unroll
            for (int nt = 0; nt < 4; nt++) {
                short8 bfr = *(const short8*)(Bs + (nq * 64 + nt * 16 + ml) * 136 + ks * 32 + quad * 8);
                acc[nt] = __builtin_amdgcn_mfma_f32_16x16x32_bf16(af, bfr, acc[nt], 0, 0, 0);
            }
        }
        __syncthreads();
    }
    // write h-tile (relu + bias) back into As (bf16, same rounding as before)
#pragma unroll
    for (int nt = 0; nt < 4; nt++) {
        int col = nq * 64 + nt * 16 + ml;
        float bv = bias1[col];
#pragma unroll
        for (int i = 0; i < 4; i++) {
            int r = mt * 16 + quad * 4 + i;
            As[r * 136 + col] = f2bf(fmaxf(acc[nt][i] + bv, 0.f));
        }
    }
    __syncthreads();

    // ---- stage 2: q / kv / skip projections from the LDS h-tile ----
#pragma unroll 1
    for (int y = 0; y < 4; y++) {
#pragma unroll
        for (int rep = 0; rep < 8; rep++) {
            int r = rbase + rep * 16;
            short8 val = *(const short8*)(Wt2 + (long)y * 16384 + (long)r * 128 + cb);
            *(short8*)(Bs + r * 136 + cb) = val;
        }
        __syncthreads();
        f32x4 acc2[4];
#pragma unroll
        for (int i = 0; i < 4; i++) acc2[i] = (f32x4){0.f, 0.f, 0.f, 0.f};
#pragma unroll
        for (int ks = 0; ks < 4; ks++) {
            short8 af = *(const short8*)(As + (mt * 16 + ml) * 136 + ks * 32 + quad * 8);
#pragma unroll
            for (int nt = 0; nt < 4; nt++) {
                short8 bfr = *(const short8*)(Bs + (nq * 64 + nt * 16 + ml) * 136 + ks * 32 + quad * 8);
                acc2[nt] = __builtin_amdgcn_mfma_f32_16x16x32_bf16(af, bfr, acc2[nt], 0, 0, 0);
            }
        }
        u16* C;
        int ldc;
        if (y == 0) { C = Cq; ldc = 128; }
        else if (y == 1) { C = Ckv; ldc = 256; }
        else if (y == 2) { C = Ckv + 128; ldc = 256; }
        else { C = Cs; ldc = 128; }
#pragma unroll
        for (int nt = 0; nt < 4; nt++) {
            int col = nq * 64 + nt * 16 + ml;
            float bv = bcat[y * 128 + col];
#pragma unroll
            for (int i = 0; i < 4; i++) {
                int gr = block_m + mt * 16 + quad * 4 + i;
                C[(long)gr * ldc + col] = f2bf(acc2[nt][i] + bv);
            }
        }
        __syncthreads();
    }
}

// ---------------- attention: 16-lane/node, 8 nodes/block, direct-exp softmax, fused KV ----------------
__global__ __launch_bounds__(128) void attn_kernel(const u16* __restrict__ q,
                                                   const u16* __restrict__ kv,
                                                   const u16* __restrict__ skip,
                                                   const int* __restrict__ row_off,
                                                   const int* __restrict__ es,
                                                   float* __restrict__ out) {
    int node = blockIdx.x * 8 + (threadIdx.x >> 4);
    int lane = threadIdx.x & 15;     // 8 dims/lane
    if (node >= NN) return;
    int p0 = row_off[node], p1 = row_off[node + 1];
    uint4 qw = *(const uint4*)(q + (long)node * 128 + lane * 8);
    float q0 = lo16(qw.x), q1 = hi16(qw.x), q2 = lo16(qw.y), q3 = hi16(qw.y);
    float q4 = lo16(qw.z), q5 = hi16(qw.z), q6 = lo16(qw.w), q7 = hi16(qw.w);
    const float SC = 0.08838834764831845f;  // 1/sqrt(128)
    float l = 0.f;
    float a0 = 0.f, a1 = 0.f, a2 = 0.f, a3 = 0.f, a4 = 0.f, a5 = 0.f, a6 = 0.f, a7 = 0.f;
    int p = p0;
    for (; p + 4 <= p1; p += 4) {
        const u16* b0 = kv + (long)es[p] * 256 + lane * 8;
        const u16* b1 = kv + (long)es[p + 1] * 256 + lane * 8;
        const u16* b2 = kv + (long)es[p + 2] * 256 + lane * 8;
        const u16* b3 = kv + (long)es[p + 3] * 256 + lane * 8;
        uint4 k0 = *(const uint4*)b0;
        uint4 k1 = *(const uint4*)b1;
        uint4 k2 = *(const uint4*)b2;
        uint4 k3 = *(const uint4*)b3;
        uint4 v0 = *(const uint4*)(b0 + 128);
        uint4 v1 = *(const uint4*)(b1 + 128);
        uint4 v2 = *(const uint4*)(b2 + 128);
        uint4 v3 = *(const uint4*)(b3 + 128);
        float t0 = q0 * lo16(k0.x) + q1 * hi16(k0.x) + q2 * lo16(k0.y) + q3 * hi16(k0.y) +
                   q4 * lo16(k0.z) + q5 * hi16(k0.z) + q6 * lo16(k0.w) + q7 * hi16(k0.w);
        float t1 = q0 * lo16(k1.x) + q1 * hi16(k1.x) + q2 * lo16(k1.y) + q3 * hi16(k1.y) +
                   q4 * lo16(k1.z) + q5 * hi16(k1.z) + q6 * lo16(k1.w) + q7 * hi16(k1.w);
        float t2 = q0 * lo16(k2.x) + q1 * hi16(k2.x) + q2 * lo16(k2.y) + q3 * hi16(k2.y) +
                   q4 * lo16(k2.z) + q5 * hi16(k2.z) + q6 * lo16(k2.w) + q7 * hi16(k2.w);
        float t3 = q0 * lo16(k3.x) + q1 * hi16(k3.x) + q2 * lo16(k3.y) + q3 * hi16(k3.y) +
                   q4 * lo16(k3.z) + q5 * hi16(k3.z) + q6 * lo16(k3.w) + q7 * hi16(k3.w);
#pragma unroll
        for (int off = 8; off >= 1; off >>= 1) {
            t0 += __shfl_xor(t0, off, 16);
            t1 += __shfl_xor(t1, off, 16);
            t2 += __shfl_xor(t2, off, 16);
            t3 += __shfl_xor(t3, off, 16);
        }
        float w0 = __expf(fminf(t0 * SC, 70.f));
        float w1 = __expf(fminf(t1 * SC, 70.f));
        float w2 = __expf(fminf(t2 * SC, 70.f));
        float w3 = __expf(fminf(t3 * SC, 70.f));
        l += (w0 + w1) + (w2 + w3);
        a0 += w0 * lo16(v0.x) + w1 * lo16(v1.x) + w2 * lo16(v2.x) + w3 * lo16(v3.x);
        a1 += w0 * hi16(v0.x) + w1 * hi16(v1.x) + w2 * hi16(v2.x) + w3 * hi16(v3.x);
        a2 += w0 * lo16(v0.y) + w1 * lo16(v1.y) + w2 * lo16(v2.y) + w3 * lo16(v3.y);
        a3 += w0 * hi16(v0.y) + w1 * hi16(v1.y) + w2 * hi16(v2.y) + w3 * hi16(v3.y);
        a4 += w0 * lo16(v0.z) + w1 * lo16(v1.z) + w2 * lo16(v2.z) + w3 * lo16(v3.z);
        a5 += w0 * hi16(v0.z) + w1 * hi16(v1.z) + w2 * hi16(v2.z) + w3 * hi16(v3.z);
        a6 += w0 * lo16(v0.w) + w1 * lo16(v1.w) + w2 * lo16(v2.w) + w3 * lo16(v3.w);
        a7 += w0 * hi16(v0.w) + w1 * hi16(v1.w) + w2 * hi16(v2.w) + w3 * hi16(v3.w);
    }
    for (; p < p1; p++) {
        const u16* b = kv + (long)es[p] * 256 + lane * 8;
        uint4 kw = *(const uint4*)b;
        uint4 vw = *(const uint4*)(b + 128);
        float t = q0 * lo16(kw.x) + q1 * hi16(kw.x) + q2 * lo16(kw.y) + q3 * hi16(kw.y) +
                  q4 * lo16(kw.z) + q5 * hi16(kw.z) + q6 * lo16(kw.w) + q7 * hi16(kw.w);
#pragma unroll
        for (int off = 8; off >= 1; off >>= 1) t += __shfl_xor(t, off, 16);
        float w = __expf(fminf(t * SC, 70.f));
        l += w;
        a0 += w * lo16(vw.x);
        a1 += w * hi16(vw.x);
        a2 += w * lo16(vw.y);
        a3 += w * hi16(vw.y);
        a4 += w * lo16(vw.z);
        a5 += w * hi16(vw.z);
        a6 += w * lo16(vw.w);
        a7 += w * hi16(vw.w);
    }
    float invl = (l > 0.f) ? 1.0f / l : 0.f;
    uint4 sw = *(const uint4*)(skip + (long)node * 128 + lane * 8);
    float4 oa, ob;
    oa.x = fmaxf(a0 * invl + lo16(sw.x), 0.f);
    oa.y = fmaxf(a1 * invl + hi16(sw.x), 0.f);
    oa.z = fmaxf(a2 * invl + lo16(sw.y), 0.f);
    oa.w = fmaxf(a3 * invl + hi16(sw.y), 0.f);
    ob.x = fmaxf(a4 * invl + lo16(sw.z), 0.f);
    ob.y = fmaxf(a5 * invl + hi16(sw.z), 0.f);
    ob.z = fmaxf(a6 * invl + lo16(sw.w), 0.f);
    ob.w = fmaxf(a7 * invl + hi16(sw.w), 0.f);
    *(float4*)(out + (long)node * 128 + lane * 8) = oa;
    *(float4*)(out + (long)node * 128 + lane * 8 + 4) = ob;
}

extern "C" void kernel_launch(void* const* d_in, const int* in_sizes, int n_in,
                              void* d_out, int out_size, void* d_ws, size_t ws_size,
                              hipStream_t stream) {
    const float* x = (const float*)d_in[0];
    const int* ei = (const int*)d_in[1];
    const int* et = (const int*)d_in[2];
    const float* rw = (const float*)d_in[3];
    const float* root = (const float*)d_in[4];
    const float* rbias = (const float*)d_in[5];
    const float* Wq = (const float*)d_in[6];
    const float* bq = (const float*)d_in[7];
    const float* Wk = (const float*)d_in[8];
    const float* bk = (const float*)d_in[9];
    const float* Wv = (const float*)d_in[10];
    const float* bv = (const float*)d_in[11];
    const float* Ws = (const float*)d_in[12];
    const float* bs = (const float*)d_in[13];

    char* ws = (char*)d_ws;
    size_t off = 0;
    auto alloc = [&](size_t b) {
        size_t o = off;
        off = (off + b + 255) & ~(size_t)255;
        return o;
    };
    u16* pre = (u16*)(ws + alloc((size_t)NN * 1152 * 2));
    u16* qv = (u16*)(ws + alloc((size_t)NN * 128 * 2));
    u16* kv = (u16*)(ws + alloc((size_t)NN * 256 * 2));
    u16* skip = (u16*)(ws + alloc((size_t)NN * 128 * 2));
    u16* xb = (u16*)(ws + alloc((size_t)NN * 128 * 2));
    u16* wt1 = (u16*)(ws + alloc((size_t)128 * 1152 * 2));
    u16* wt2 = (u16*)(ws + alloc((size_t)4 * 128 * 128 * 2));
    float* bcat = (float*)(ws + alloc((size_t)512 * 4));
    int* cnt = (int*)(ws + alloc((size_t)NN * 8 * 4));
    int* row_off = (int*)(ws + alloc((size_t)(NN + 1) * 4));
    int* srt = (int*)(ws + alloc((size_t)NN * 8 * 4));
    int* deg_pref = (int*)(ws + alloc((size_t)NN * 4));
    int* blk_sums = (int*)(ws + alloc((size_t)128 * 4));
    int* rank = (int*)(ws + alloc((size_t)EE * 4));
    int* es = (int*)(ws + alloc((size_t)EE * 4));
    (void)ws_size;
    (void)in_sizes;
    (void)n_in;
    (void)out_size;

    prep_all<<<(ZP_N + CX_N + WP_N + 255) / 256, 256, 0, stream>>>(
        x, rw, root, Wq, Wk, Wv, Ws, bq, bk, bv, bs, cnt, xb, wt1, wt2, bcat);

    count_rank<<<(EE + 2047) / 2048, 256, 0, stream>>>(ei, et, cnt, rank);
    scan_phase1<<<SCAN_BLOCKS, 256, 0, stream>>>(cnt, deg_pref, blk_sums);
    scan_phase3<<<SCAN_BLOCKS, 256, 0, stream>>>(cnt, deg_pref, blk_sums, row_off, srt);
    scatter_kernel<<<(EE + 2047) / 2048, 256, 0, stream>>>(ei, et, srt, rank, es);

    rgcn_agg<<<(NN * 9 + 15) / 16, 256, 0, stream>>>(xb, srt, cnt, es, pre);

    gemm_fused<<<NN / 32, 256, 0, stream>>>(pre, wt1, rbias, wt2, bcat, qv, kv, skip);

    attn_kernel<<<(NN + 7) / 8, 128, 0, stream>>>(qv, kv, skip, row_off, es, (float*)d_out);
}

// Round 13
// 231.862 us; speedup vs baseline: 1.1301x; 1.0147x over previous
//
#include <hip/hip_runtime.h>

typedef unsigned short u16;
typedef unsigned int u32;
typedef __attribute__((ext_vector_type(8))) short short8;
typedef __attribute__((ext_vector_type(4))) float f32x4;

#define NN 20000
#define EE 640000
#define SCAN_BLOCKS 80   // 80*256 = 20480 >= NN

__device__ inline u16 f2bf(float f) {
    u32 x = __float_as_uint(f);
    return (u16)((x + 0x7FFFu + ((x >> 16) & 1u)) >> 16);
}
__device__ inline float lo16(u32 w) { return __uint_as_float(w << 16); }
__device__ inline float hi16(u32 w) { return __uint_as_float(w & 0xFFFF0000u); }
__device__ inline u32 packbf(float a, float b) { return ((u32)f2bf(b) << 16) | (u32)f2bf(a); }

// ---------------- fused prep + edge count (independent work overlapped in one launch) ----------------
// segment 0 (first CT_N threads): count 8 edges each (atomics start earliest)
// segment 1: cast x->bf16 into xb AND pre tail (slot-8 of rgcn fused here)
// segment 2: weight transpose/cast
#define CT_N (EE / 8)                                   // 80000 counting threads
#define CX_N (NN * 32)                                  // 640000 float4 casts
#define WP_N (128 * 1152 + 4 * 128 * 128 + 512)
__global__ __launch_bounds__(256) void prep_count(const int* __restrict__ ei,
                                                  const int* __restrict__ et,
                                                  int* __restrict__ cnt, int* __restrict__ rank,
                                                  const float* __restrict__ x,
                                                  const float* rw, const float* root,
                                                  const float* Wq, const float* Wk,
                                                  const float* Wv, const float* Ws,
                                                  const float* bq, const float* bk,
                                                  const float* bv, const float* bs,
                                                  u16* __restrict__ xb, u16* __restrict__ pre,
                                                  u16* wt1, u16* wt2, float* bcat) {
    int idx = blockIdx.x * 256 + threadIdx.x;
    if (idx < CT_N) {
#pragma unroll
        for (int j = 0; j < 8; j++) {
            int e = idx + j * CT_N;
            int dst = ei[EE + e];
            int r = et[e];
            rank[e] = atomicAdd(&cnt[dst * 8 + r], 1);
        }
        return;
    }
    idx -= CT_N;
    if (idx < CX_N) {
        float4 v = *(const float4*)(x + (size_t)idx * 4);
        uint2 o;
        o.x = packbf(v.x, v.y);
        o.y = packbf(v.z, v.w);
        *(uint2*)(xb + (size_t)idx * 4) = o;
        int node = idx >> 5;
        int d = (idx & 31) * 4;
        *(uint2*)(pre + (long)node * 1152 + 1024 + d) = o;   // rgcn slot-8 fused
        return;
    }
    idx -= CX_N;
    const int S1 = 128 * 1152, S2 = 4 * 128 * 128;
    if (idx < S1) {
        int o = idx / 1152, k = idx - o * 1152;
        float v = (k < 1024) ? rw[k * 128 + o] : root[(k - 1024) * 128 + o];
        wt1[idx] = f2bf(v);
    } else if (idx < S1 + S2) {
        int j = idx - S1;
        int y = j >> 14, rem = j & 16383, o = rem >> 7, i = rem & 127;
        const float* W = (y == 0) ? Wq : (y == 1) ? Wk : (y == 2) ? Wv : Ws;
        wt2[j] = f2bf(W[i * 128 + o]);
    } else if (idx < S1 + S2 + 512) {
        int j = idx - (S1 + S2);
        int y = j >> 7, c = j & 127;
        const float* b = (y == 0) ? bq : (y == 1) ? bk : (y == 2) ? bv : bs;
        bcat[j] = b[c];
    }
}

// ---------------- parallel scan (2 kernels) ----------------
__global__ __launch_bounds__(256) void scan_phase1(const int* __restrict__ cnt,
                                                   int* __restrict__ deg_pref,
                                                   int* __restrict__ blk_sums) {
    __shared__ int lds[256];
    int t = threadIdx.x;
    int n = blockIdx.x * 256 + t;
    int d = 0;
    if (n < NN) {
        int4 c0 = *(const int4*)(cnt + n * 8);
        int4 c1 = *(const int4*)(cnt + n * 8 + 4);
        d = c0.x + c0.y + c0.z + c0.w + c1.x + c1.y + c1.z + c1.w;
    }
    lds[t] = d;
    __syncthreads();
    for (int o = 1; o < 256; o <<= 1) {
        int v = (t >= o) ? lds[t - o] : 0;
        __syncthreads();
        lds[t] += v;
        __syncthreads();
    }
    if (n < NN) deg_pref[n] = lds[t];
    if (t == 255) blk_sums[blockIdx.x] = lds[255];
}

__global__ __launch_bounds__(256) void scan_phase3(const int* __restrict__ cnt,
                                                   const int* __restrict__ deg_pref,
                                                   const int* __restrict__ blk_sums,
                                                   int* __restrict__ row_off,
                                                   int* __restrict__ srt) {
    __shared__ int bs_lds[128];
    int t = threadIdx.x;
    if (t < 128) {
        int v = (t < SCAN_BLOCKS) ? blk_sums[t] : 0;
        bs_lds[t] = v;
    }
    __syncthreads();
    if (t < 128) {
        for (int o = 1; o < 128; o <<= 1) {
            int a = (t >= o) ? bs_lds[t - o] : 0;
            __syncthreads();
            bs_lds[t] += a;
            __syncthreads();
        }
    } else {
        for (int o = 1; o < 128; o <<= 1) {
            __syncthreads();
            __syncthreads();
        }
    }
    int blk_excl = (blockIdx.x > 0) ? bs_lds[blockIdx.x - 1] : 0;
    int n = blockIdx.x * 256 + t;
    if (n >= NN) return;
    int4 c0 = *(const int4*)(cnt + n * 8);
    int4 c1 = *(const int4*)(cnt + n * 8 + 4);
    int deg = c0.x + c0.y + c0.z + c0.w + c1.x + c1.y + c1.z + c1.w;
    int start = blk_excl + deg_pref[n] - deg;   // exclusive global prefix
    row_off[n] = start;
    int sub = start;
    int o[8];
    o[0] = sub; sub += c0.x;
    o[1] = sub; sub += c0.y;
    o[2] = sub; sub += c0.z;
    o[3] = sub; sub += c0.w;
    o[4] = sub; sub += c1.x;
    o[5] = sub; sub += c1.y;
    o[6] = sub; sub += c1.z;
    o[7] = sub; sub += c1.w;
    *(int4*)(srt + n * 8) = make_int4(o[0], o[1], o[2], o[3]);
    *(int4*)(srt + n * 8 + 4) = make_int4(o[4], o[5], o[6], o[7]);
    if (n == NN - 1) row_off[NN] = sub;
}

// atomic-free scatter, 8 edges/thread
__global__ void scatter_kernel(const int* __restrict__ ei, const int* __restrict__ et,
                               const int* __restrict__ srt, const int* __restrict__ rank,
                               int* __restrict__ es) {
    int base = blockIdx.x * 2048 + threadIdx.x;
#pragma unroll
    for (int j = 0; j < 8; j++) {
        int e = base + j * 256;
        if (e < EE) {
            int dst = ei[EE + e];
            int src = ei[e];
            int r = et[e];
            es[srt[dst * 8 + r] + rank[e]] = src;
        }
    }
}

// ---------------- RGCN pre-aggregation: 16-lane group per (node,relation) ----------------
__global__ __launch_bounds__(256) void rgcn_agg(const u16* __restrict__ xb,
                                                const int* __restrict__ srt,
                                                const int* __restrict__ cnt,
                                                const int* __restrict__ es,
                                                u16* __restrict__ pre) {
    int gid = blockIdx.x * 16 + (threadIdx.x >> 4);
    int lane = threadIdx.x & 15;     // 8 dims/lane
    if (gid >= NN * 8) return;
    int node = gid >> 3;
    int slot = gid & 7;
    int c = cnt[node * 8 + slot];
    int p0 = srt[node * 8 + slot];
    float inv = 1.0f / (float)(c > 1 ? c : 1);
    float a0 = 0.f, a1 = 0.f, a2 = 0.f, a3 = 0.f, a4 = 0.f, a5 = 0.f, a6 = 0.f, a7 = 0.f;
    int i = 0;
    for (; i + 4 <= c; i += 4) {
        int s0 = es[p0 + i], s1 = es[p0 + i + 1], s2 = es[p0 + i + 2], s3 = es[p0 + i + 3];
        uint4 w0 = *(const uint4*)(xb + (long)s0 * 128 + lane * 8);
        uint4 w1 = *(const uint4*)(xb + (long)s1 * 128 + lane * 8);
        uint4 w2 = *(const uint4*)(xb + (long)s2 * 128 + lane * 8);
        uint4 w3 = *(const uint4*)(xb + (long)s3 * 128 + lane * 8);
        a0 += (lo16(w0.x) + lo16(w1.x)) + (lo16(w2.x) + lo16(w3.x));
        a1 += (hi16(w0.x) + hi16(w1.x)) + (hi16(w2.x) + hi16(w3.x));
        a2 += (lo16(w0.y) + lo16(w1.y)) + (lo16(w2.y) + lo16(w3.y));
        a3 += (hi16(w0.y) + hi16(w1.y)) + (hi16(w2.y) + hi16(w3.y));
        a4 += (lo16(w0.z) + lo16(w1.z)) + (lo16(w2.z) + lo16(w3.z));
        a5 += (hi16(w0.z) + hi16(w1.z)) + (hi16(w2.z) + hi16(w3.z));
        a6 += (lo16(w0.w) + lo16(w1.w)) + (lo16(w2.w) + lo16(w3.w));
        a7 += (hi16(w0.w) + hi16(w1.w)) + (hi16(w2.w) + hi16(w3.w));
    }
    for (; i < c; i++) {
        int s = es[p0 + i];
        uint4 w = *(const uint4*)(xb + (long)s * 128 + lane * 8);
        a0 += lo16(w.x); a1 += hi16(w.x); a2 += lo16(w.y); a3 += hi16(w.y);
        a4 += lo16(w.z); a5 += hi16(w.z); a6 += lo16(w.w); a7 += hi16(w.w);
    }
    uint4 ow;
    ow.x = packbf(a0 * inv, a1 * inv);
    ow.y = packbf(a2 * inv, a3 * inv);
    ow.z = packbf(a4 * inv, a5 * inv);
    ow.w = packbf(a6 * inv, a7 * inv);
    *(uint4*)(pre + (long)node * 1152 + slot * 128 + lane * 8) = ow;
}

// ---------------- fused GEMM: h=relu(pre@W1+b1) kept in LDS, then q/kv/skip = h@Wy+by ----------------
__global__ __launch_bounds__(256) void gemm_fused(const u16* __restrict__ A,
                                                  const u16* __restrict__ Bt1,
                                                  const float* __restrict__ bias1,
                                                  const u16* __restrict__ Wt2,
                                                  const float* __restrict__ bcat,
                                                  u16* __restrict__ Cq, u16* __restrict__ Ckv,
                                                  u16* __restrict__ Cs) {
    __shared__ u16 As[32 * 136];
    __shared__ u16 Bs[128 * 136];
    int tid = threadIdx.x;
    int w = tid >> 6;
    int lane = tid & 63;
    int quad = lane >> 4;
    int ml = lane & 15;
    int mt = w & 1;
    int nq = w >> 1;
    int block_m = blockIdx.x * 32;

    f32x4 acc[4];
#pragma unroll
    for (int i = 0; i < 4; i++) acc[i] = (f32x4){0.f, 0.f, 0.f, 0.f};

    int rbase = tid >> 4;
    int cb = (tid & 15) * 8;

    // ---- stage 1: h-tile = relu(pre-tile @ wt1^T + b1) ----
    for (int kb = 0; kb < 1152; kb += 128) {
#pragma unroll
        for (int rep = 0; rep < 2; rep++) {
            int r = rbase + rep * 16;
            short8 val = *(const short8*)(A + (long)(block_m + r) * 1152 + kb + cb);
            *(short8*)(As + r * 136 + cb) = val;
        }
#pragma unroll
        for (int rep = 0; rep < 8; rep++) {
            int r = rbase + rep * 16;
            short8 val = *(const short8*)(Bt1 + (long)r * 1152 + kb + cb);
            *(short8*)(Bs + r * 136 + cb) = val;
        }
        __syncthreads();
#pragma unroll
        for (int ks = 0; ks < 4; ks++) {
            short8 af = *(const short8*)(As + (mt * 16 + ml) * 136 + ks * 32 + quad * 8);
#pragma unroll
            for (int nt = 0; nt < 4; nt++) {
                short8 bfr = *(const short8*)(Bs + (nq * 64 + nt * 16 + ml) * 136 + ks * 32 + quad * 8);
                acc[nt] = __builtin_amdgcn_mfma_f32_16x16x32_bf16(af, bfr, acc[nt], 0, 0, 0);
            }
        }
        __syncthreads();
    }
#pragma unroll
    for (int nt = 0; nt < 4; nt++) {
        int col = nq * 64 + nt * 16 + ml;
        float bv = bias1[col];
#pragma unroll
        for (int i = 0; i < 4; i++) {
            int r = mt * 16 + quad * 4 + i;
            As[r * 136 + col] = f2bf(fmaxf(acc[nt][i] + bv, 0.f));
        }
    }
    __syncthreads();

    // ---- stage 2: q / kv / skip projections from the LDS h-tile ----
#pragma unroll 1
    for (int y = 0; y < 4; y++) {
#pragma unroll
        for (int rep = 0; rep < 8; rep++) {
            int r = rbase + rep * 16;
            short8 val = *(const short8*)(Wt2 + (long)y * 16384 + (long)r * 128 + cb);
            *(short8*)(Bs + r * 136 + cb) = val;
        }
        __syncthreads();
        f32x4 acc2[4];
#pragma unroll
        for (int i = 0; i < 4; i++) acc2[i] = (f32x4){0.f, 0.f, 0.f, 0.f};
#pragma unroll
        for (int ks = 0; ks < 4; ks++) {
            short8 af = *(const short8*)(As + (mt * 16 + ml) * 136 + ks * 32 + quad * 8);
#pragma unroll
            for (int nt = 0; nt < 4; nt++) {
                short8 bfr = *(const short8*)(Bs + (nq * 64 + nt * 16 + ml) * 136 + ks * 32 + quad * 8);
                acc2[nt] = __builtin_amdgcn_mfma_f32_16x16x32_bf16(af, bfr, acc2[nt], 0, 0, 0);
            }
        }
        u16* C;
        int ldc;
        if (y == 0) { C = Cq; ldc = 128; }
        else if (y == 1) { C = Ckv; ldc = 256; }
        else if (y == 2) { C = Ckv + 128; ldc = 256; }
        else { C = Cs; ldc = 128; }
#pragma unroll
        for (int nt = 0; nt < 4; nt++) {
            int col = nq * 64 + nt * 16 + ml;
            float bv = bcat[y * 128 + col];
#pragma unroll
            for (int i = 0; i < 4; i++) {
                int gr = block_m + mt * 16 + quad * 4 + i;
                C[(long)gr * ldc + col] = f2bf(acc2[nt][i] + bv);
            }
        }
        __syncthreads();
    }
}

// ---------------- attention: 16-lane/node, 8 nodes/block, direct-exp softmax, fused KV ----------------
__global__ __launch_bounds__(128) void attn_kernel(const u16* __restrict__ q,
                                                   const u16* __restrict__ kv,
                                                   const u16* __restrict__ skip,
                                                   const int* __restrict__ row_off,
                                                   const int* __restrict__ es,
                                                   float* __restrict__ out) {
    int node = blockIdx.x * 8 + (threadIdx.x >> 4);
    int lane = threadIdx.x & 15;     // 8 dims/lane
    if (node >= NN) return;
    int p0 = row_off[node], p1 = row_off[node + 1];
    uint4 qw = *(const uint4*)(q + (long)node * 128 + lane * 8);
    float q0 = lo16(qw.x), q1 = hi16(qw.x), q2 = lo16(qw.y), q3 = hi16(qw.y);
    float q4 = lo16(qw.z), q5 = hi16(qw.z), q6 = lo16(qw.w), q7 = hi16(qw.w);
    const float SC = 0.08838834764831845f;  // 1/sqrt(128)
    float l = 0.f;
    float a0 = 0.f, a1 = 0.f, a2 = 0.f, a3 = 0.f, a4 = 0.f, a5 = 0.f, a6 = 0.f, a7 = 0.f;
    int p = p0;
    for (; p + 4 <= p1; p += 4) {
        const u16* b0 = kv + (long)es[p] * 256 + lane * 8;
        const u16* b1 = kv + (long)es[p + 1] * 256 + lane * 8;
        const u16* b2 = kv + (long)es[p + 2] * 256 + lane * 8;
        const u16* b3 = kv + (long)es[p + 3] * 256 + lane * 8;
        uint4 k0 = *(const uint4*)b0;
        uint4 k1 = *(const uint4*)b1;
        uint4 k2 = *(const uint4*)b2;
        uint4 k3 = *(const uint4*)b3;
        uint4 v0 = *(const uint4*)(b0 + 128);
        uint4 v1 = *(const uint4*)(b1 + 128);
        uint4 v2 = *(const uint4*)(b2 + 128);
        uint4 v3 = *(const uint4*)(b3 + 128);
        float t0 = q0 * lo16(k0.x) + q1 * hi16(k0.x) + q2 * lo16(k0.y) + q3 * hi16(k0.y) +
                   q4 * lo16(k0.z) + q5 * hi16(k0.z) + q6 * lo16(k0.w) + q7 * hi16(k0.w);
        float t1 = q0 * lo16(k1.x) + q1 * hi16(k1.x) + q2 * lo16(k1.y) + q3 * hi16(k1.y) +
                   q4 * lo16(k1.z) + q5 * hi16(k1.z) + q6 * lo16(k1.w) + q7 * hi16(k1.w);
        float t2 = q0 * lo16(k2.x) + q1 * hi16(k2.x) + q2 * lo16(k2.y) + q3 * hi16(k2.y) +
                   q4 * lo16(k2.z) + q5 * hi16(k2.z) + q6 * lo16(k2.w) + q7 * hi16(k2.w);
        float t3 = q0 * lo16(k3.x) + q1 * hi16(k3.x) + q2 * lo16(k3.y) + q3 * hi16(k3.y) +
                   q4 * lo16(k3.z) + q5 * hi16(k3.z) + q6 * lo16(k3.w) + q7 * hi16(k3.w);
#pragma unroll
        for (int off = 8; off >= 1; off >>= 1) {
            t0 += __shfl_xor(t0, off, 16);
            t1 += __shfl_xor(t1, off, 16);
            t2 += __shfl_xor(t2, off, 16);
            t3 += __shfl_xor(t3, off, 16);
        }
        float w0 = __expf(fminf(t0 * SC, 70.f));
        float w1 = __expf(fminf(t1 * SC, 70.f));
        float w2 = __expf(fminf(t2 * SC, 70.f));
        float w3 = __expf(fminf(t3 * SC, 70.f));
        l += (w0 + w1) + (w2 + w3);
        a0 += w0 * lo16(v0.x) + w1 * lo16(v1.x) + w2 * lo16(v2.x) + w3 * lo16(v3.x);
        a1 += w0 * hi16(v0.x) + w1 * hi16(v1.x) + w2 * hi16(v2.x) + w3 * hi16(v3.x);
        a2 += w0 * lo16(v0.y) + w1 * lo16(v1.y) + w2 * lo16(v2.y) + w3 * lo16(v3.y);
        a3 += w0 * hi16(v0.y) + w1 * hi16(v1.y) + w2 * hi16(v2.y) + w3 * hi16(v3.y);
        a4 += w0 * lo16(v0.z) + w1 * lo16(v1.z) + w2 * lo16(v2.z) + w3 * lo16(v3.z);
        a5 += w0 * hi16(v0.z) + w1 * hi16(v1.z) + w2 * hi16(v2.z) + w3 * hi16(v3.z);
        a6 += w0 * lo16(v0.w) + w1 * lo16(v1.w) + w2 * lo16(v2.w) + w3 * lo16(v3.w);
        a7 += w0 * hi16(v0.w) + w1 * hi16(v1.w) + w2 * hi16(v2.w) + w3 * hi16(v3.w);
    }
    for (; p < p1; p++) {
        const u16* b = kv + (long)es[p] * 256 + lane * 8;
        uint4 kw = *(const uint4*)b;
        uint4 vw = *(const uint4*)(b + 128);
        float t = q0 * lo16(kw.x) + q1 * hi16(kw.x) + q2 * lo16(kw.y) + q3 * hi16(kw.y) +
                  q4 * lo16(kw.z) + q5 * hi16(kw.z) + q6 * lo16(kw.w) + q7 * hi16(kw.w);
#pragma unroll
        for (int off = 8; off >= 1; off >>= 1) t += __shfl_xor(t, off, 16);
        float w = __expf(fminf(t * SC, 70.f));
        l += w;
        a0 += w * lo16(vw.x);
        a1 += w * hi16(vw.x);
        a2 += w * lo16(vw.y);
        a3 += w * hi16(vw.y);
        a4 += w * lo16(vw.z);
        a5 += w * hi16(vw.z);
        a6 += w * lo16(vw.w);
        a7 += w * hi16(vw.w);
    }
    float invl = (l > 0.f) ? 1.0f / l : 0.f;
    uint4 sw = *(const uint4*)(skip + (long)node * 128 + lane * 8);
    float4 oa, ob;
    oa.x = fmaxf(a0 * invl + lo16(sw.x), 0.f);
    oa.y = fmaxf(a1 * invl + hi16(sw.x), 0.f);
    oa.z = fmaxf(a2 * invl + lo16(sw.y), 0.f);
    oa.w = fmaxf(a3 * invl + hi16(sw.y), 0.f);
    ob.x = fmaxf(a4 * invl + lo16(sw.z), 0.f);
    ob.y = fmaxf(a5 * invl + hi16(sw.z), 0.f);
    ob.z = fmaxf(a6 * invl + lo16(sw.w), 0.f);
    ob.w = fmaxf(a7 * invl + hi16(sw.w), 0.f);
    *(float4*)(out + (long)node * 128 + lane * 8) = oa;
    *(float4*)(out + (long)node * 128 + lane * 8 + 4) = ob;
}

extern "C" void kernel_launch(void* const* d_in, const int* in_sizes, int n_in,
                              void* d_out, int out_size, void* d_ws, size_t ws_size,
                              hipStream_t stream) {
    const float* x = (const float*)d_in[0];
    const int* ei = (const int*)d_in[1];
    const int* et = (const int*)d_in[2];
    const float* rw = (const float*)d_in[3];
    const float* root = (const float*)d_in[4];
    const float* rbias = (const float*)d_in[5];
    const float* Wq = (const float*)d_in[6];
    const float* bq = (const float*)d_in[7];
    const float* Wk = (const float*)d_in[8];
    const float* bk = (const float*)d_in[9];
    const float* Wv = (const float*)d_in[10];
    const float* bv = (const float*)d_in[11];
    const float* Ws = (const float*)d_in[12];
    const float* bs = (const float*)d_in[13];

    char* ws = (char*)d_ws;
    size_t off = 0;
    auto alloc = [&](size_t b) {
        size_t o = off;
        off = (off + b + 255) & ~(size_t)255;
        return o;
    };
    u16* pre = (u16*)(ws + alloc((size_t)NN * 1152 * 2));
    u16* qv = (u16*)(ws + alloc((size_t)NN * 128 * 2));
    u16* kv = (u16*)(ws + alloc((size_t)NN * 256 * 2));
    u16* skip = (u16*)(ws + alloc((size_t)NN * 128 * 2));
    u16* xb = (u16*)(ws + alloc((size_t)NN * 128 * 2));
    u16* wt1 = (u16*)(ws + alloc((size_t)128 * 1152 * 2));
    u16* wt2 = (u16*)(ws + alloc((size_t)4 * 128 * 128 * 2));
    float* bcat = (float*)(ws + alloc((size_t)512 * 4));
    int* cnt = (int*)(ws + alloc((size_t)NN * 8 * 4));
    int* row_off = (int*)(ws + alloc((size_t)(NN + 1) * 4));
    int* srt = (int*)(ws + alloc((size_t)NN * 8 * 4));
    int* deg_pref = (int*)(ws + alloc((size_t)NN * 4));
    int* blk_sums = (int*)(ws + alloc((size_t)128 * 4));
    int* rank = (int*)(ws + alloc((size_t)EE * 4));
    int* es = (int*)(ws + alloc((size_t)EE * 4));
    (void)ws_size;
    (void)in_sizes;
    (void)n_in;
    (void)out_size;

    hipMemsetAsync(cnt, 0, (size_t)NN * 8 * 4, stream);

    prep_count<<<(CT_N + CX_N + WP_N + 255) / 256, 256, 0, stream>>>(
        ei, et, cnt, rank, x, rw, root, Wq, Wk, Wv, Ws, bq, bk, bv, bs,
        xb, pre, wt1, wt2, bcat);

    scan_phase1<<<SCAN_BLOCKS, 256, 0, stream>>>(cnt, deg_pref, blk_sums);
    scan_phase3<<<SCAN_BLOCKS, 256, 0, stream>>>(cnt, deg_pref, blk_sums, row_off, srt);
    scatter_kernel<<<(EE + 2047) / 2048, 256, 0, stream>>>(ei, et, srt, rank, es);

    rgcn_agg<<<(NN * 8 + 15) / 16, 256, 0, stream>>>(xb, srt, cnt, es, pre);

    gemm_fused<<<NN / 32, 256, 0, stream>>>(pre, wt1, rbias, wt2, bcat, qv, kv, skip);

    attn_kernel<<<(NN + 7) / 8, 128, 0, stream>>>(qv, kv, skip, row_off, es, (float*)d_out);
}